// Round 6
// baseline (486.405 us; speedup 1.0000x reference)
//
#include <hip/hip_runtime.h>
#include <cstdint>
#include <cstddef>

// ---- problem constants ----
#define D_MODEL 2048
#define D_INNER 4096
#define D_IN2   8192
#define D_STATE 16
#define D_CONVK 4
#define DT_RANK 128
#define BATCH   2
#define SEQLEN  1024
#define BL      (BATCH*SEQLEN)
#define XDBL_N  (DT_RANK + 2*D_STATE)   // 160
#define XPW_NPAD 256
#define XPROJ_SPLITS 8
#define OUT_SPLITS 2

// chunked-scan constants
#define NCHUNK  16
#define LCHUNK  (SEQLEN/NCHUNK)         // 64
#define CHW     (BATCH*D_INNER*D_STATE) // 131072

// fused-cast segment block counts (256 thr/block, 1 uint4 out/thread)
#define NB_HID   2048
#define NB_IPW   8192
#define NB_XPW   320
#define NB_XPWZ  192
#define NB_DTW   256
#define NB_OPW   4096
#define NB_XDBLZ 320

typedef short  s8v  __attribute__((ext_vector_type(8)));
typedef float  f4v  __attribute__((ext_vector_type(4)));

__device__ __forceinline__ float softplus_f(float v) {
    return (v > 20.f) ? v : log1pf(__expf(v));
}
__device__ __forceinline__ float silu_f(float v) {
    return v / (1.f + __expf(-v));
}
__device__ __forceinline__ float bf2f(short s) {
    return __uint_as_float(((uint32_t)(uint16_t)s) << 16);
}
__device__ __forceinline__ uint16_t f2bf(float f) {
    uint32_t u = __float_as_uint(f);
    return (uint16_t)((u + 0x7FFFu + ((u >> 16) & 1u)) >> 16);
}
__device__ __forceinline__ uint32_t packbf(float lo, float hi) {
    return ((uint32_t)f2bf(hi) << 16) | (uint32_t)f2bf(lo);
}
__device__ __forceinline__ float quad_sum(float p) {
    p += __int_as_float(__builtin_amdgcn_update_dpp(
            0, __float_as_int(p), 0xB1, 0xF, 0xF, true));
    p += __int_as_float(__builtin_amdgcn_update_dpp(
            0, __float_as_int(p), 0x4E, 0xF, 0xF, true));
    return p;
}

#define GLD16(gp, lp)                                                          \
    __builtin_amdgcn_global_load_lds(                                          \
        (const __attribute__((address_space(1))) void*)(gp),                   \
        (__attribute__((address_space(3))) void*)(lp), 16, 0, 0)

// ---- fused: all fp32->bf16 casts + zero-fills, one dispatch ----
__global__ __launch_bounds__(256)
void k_cast_all(const float* __restrict__ s0, uint32_t* __restrict__ d0,
                const float* __restrict__ s1, uint32_t* __restrict__ d1,
                const float* __restrict__ s2, uint32_t* __restrict__ d2,
                const float* __restrict__ s3, uint32_t* __restrict__ d3,
                const float* __restrict__ s4, uint32_t* __restrict__ d4,
                uint32_t* __restrict__ z0, uint32_t* __restrict__ z1)
{
    int blk = blockIdx.x;
    const float* src = nullptr; uint32_t* dst; int base; int zero = 0;
    if      (blk < NB_HID) { src = s0; dst = d0; base = blk; }
    else if ((blk -= NB_HID)  < NB_IPW)  { src = s1; dst = d1; base = blk; }
    else if ((blk -= NB_IPW)  < NB_XPW)  { src = s2; dst = d2; base = blk; }
    else if ((blk -= NB_XPW)  < NB_XPWZ) { dst = z0; base = blk; zero = 1; }
    else if ((blk -= NB_XPWZ) < NB_DTW)  { src = s3; dst = d3; base = blk; }
    else if ((blk -= NB_DTW)  < NB_OPW)  { src = s4; dst = d4; base = blk; }
    else                                 { dst = z1; base = blk - NB_OPW; zero = 1; }
    const int i = base * 256 + threadIdx.x;
    if (zero) { ((uint4*)dst)[i] = make_uint4(0u, 0u, 0u, 0u); return; }
    const float4 a = ((const float4*)src)[i * 2];
    const float4 b = ((const float4*)src)[i * 2 + 1];
    uint4 o;
    o.x = packbf(a.x, a.y); o.y = packbf(a.z, a.w);
    o.z = packbf(b.x, b.y); o.w = packbf(b.z, b.w);
    ((uint4*)dst)[i] = o;
}

// ---- bf16 MFMA GEMM body: C[m,n] = sum_k A[m,k]*W[n,k], BK=64, swizzled ----
// EPI: 0 = fp32 LDS-coalesced store to slice blockIdx.z,
//      2 = bf16 LDS-coalesced store,
//      3 = fp32 atomicAdd (xproj, tiny output).
template<int EPI>
__device__ __forceinline__
void gemm_body(const short* __restrict__ A, int lda,
               const short* __restrict__ W, int ldw,
               void* __restrict__ Cv, int ldc, int M, int kchunk)
{
    constexpr int SMEM_BYTES = (EPI == 2) ? 34816 : (EPI == 0) ? 33792 : 32768;
    __shared__ __align__(16) char smem[SMEM_BYTES];
    short* sA = (short*)smem;             // 128x64 bf16 = 16 KB
    short* sW = (short*)(smem + 16384);   // 128x64 bf16 = 16 KB

    const int tid = threadIdx.x;
    const int w   = tid >> 6;
    const int L   = tid & 63;
    const int bm  = blockIdx.y * 128;
    const int bn  = blockIdx.x * 128;
    const int k0  = blockIdx.z * kchunk;

    const int rsub = L >> 3;
    const int c8   = (((L & 7) - rsub) & 7) * 8;
    const short* Ag[4]; const short* Wg[4];
#pragma unroll
    for (int j = 0; j < 4; j++) {
        Ag[j] = A + (size_t)(bm + w * 32 + j * 8 + rsub) * lda + c8 + k0;
        Wg[j] = W + (size_t)(bn + w * 32 + j * 8 + rsub) * ldw + c8 + k0;
    }

    const int wm = (w >> 1) * 64;
    const int wn = (w & 1) * 64;
    const int cl = L & 15;
    const int qd = L >> 4;

    f4v acc[4][4];
#pragma unroll
    for (int i = 0; i < 4; i++)
#pragma unroll
        for (int j = 0; j < 4; j++) acc[i][j] = (f4v){0.f, 0.f, 0.f, 0.f};

    for (int k = 0; k < kchunk; k += 64) {
#pragma unroll
        for (int j = 0; j < 4; j++)
            GLD16(Ag[j] + k, &sA[(w * 32 + j * 8) * 64]);
#pragma unroll
        for (int j = 0; j < 4; j++)
            GLD16(Wg[j] + k, &sW[(w * 32 + j * 8) * 64]);
        __syncthreads();
#pragma unroll
        for (int kk = 0; kk < 2; kk++) {
            const int sl = ((kk * 4 + qd + cl) & 7) * 8;
            s8v a[4], b[4];
#pragma unroll
            for (int mt = 0; mt < 4; mt++)
                a[mt] = *(const s8v*)&sA[(wm + mt * 16 + cl) * 64 + sl];
#pragma unroll
            for (int nt = 0; nt < 4; nt++)
                b[nt] = *(const s8v*)&sW[(wn + nt * 16 + cl) * 64 + sl];
#pragma unroll
            for (int mt = 0; mt < 4; mt++)
#pragma unroll
                for (int nt = 0; nt < 4; nt++)
                    acc[mt][nt] = __builtin_amdgcn_mfma_f32_16x16x32_bf16(
                        a[mt], b[nt], acc[mt][nt], 0, 0, 0);
        }
        __syncthreads();   // also fences staging before epilogue smem reuse
    }

    if constexpr (EPI == 2) {
        ushort (*sC)[136] = (ushort(*)[136])smem;
        short* Cs = (short*)Cv;
#pragma unroll
        for (int mt = 0; mt < 4; mt++)
#pragma unroll
            for (int nt = 0; nt < 4; nt++)
#pragma unroll
                for (int r = 0; r < 4; r++)
                    sC[wm + mt * 16 + qd * 4 + r][wn + nt * 16 + cl] =
                        (ushort)f2bf(acc[mt][nt][r]);
        __syncthreads();
#pragma unroll
        for (int it = 0; it < 8; it++) {
            const int idx = it * 256 + tid;
            const int row = idx >> 4;          // 128 rows
            const int c8s = (idx & 15) * 8;    // 16B chunks, 256B/row
            *(uint4*)&Cs[(size_t)(bm + row) * ldc + bn + c8s] =
                *(const uint4*)&sC[row][c8s];
        }
    } else if constexpr (EPI == 0) {
        float (*sC)[132] = (float(*)[132])smem;
        float* Cf = (float*)Cv + (size_t)blockIdx.z * M * ldc;
#pragma unroll
        for (int half = 0; half < 2; half++) {
            __syncthreads();
            if (wm == half * 64) {
#pragma unroll
                for (int mt = 0; mt < 4; mt++)
#pragma unroll
                    for (int nt = 0; nt < 4; nt++)
#pragma unroll
                        for (int r = 0; r < 4; r++)
                            sC[mt * 16 + qd * 4 + r][wn + nt * 16 + cl] =
                                acc[mt][nt][r];
            }
            __syncthreads();
#pragma unroll
            for (int it = 0; it < 8; it++) {
                const int f4  = it * 256 + tid;
                const int row = f4 >> 5;
                const int c4  = (f4 & 31) * 4;
                const float4 v = *(const float4*)&sC[row][c4];
                *(float4*)&Cf[(size_t)(bm + half * 64 + row) * ldc + bn + c4] = v;
            }
        }
    } else {
        float* Cf = (float*)Cv;
#pragma unroll
        for (int mt = 0; mt < 4; mt++) {
            const int row0 = bm + wm + mt * 16 + qd * 4;
#pragma unroll
            for (int nt = 0; nt < 4; nt++) {
                const int col = bn + wn + nt * 16 + cl;
                if (col >= XDBL_N) continue;
#pragma unroll
                for (int r = 0; r < 4; r++)
                    atomicAdd(&Cf[(size_t)(row0 + r) * ldc + col], acc[mt][nt][r]);
            }
        }
    }
}

// named entry points (profiling visibility)
__global__ __launch_bounds__(256)
void k_gemm_inproj(const short* A, const short* W, short* C)
{ gemm_body<2>(A, D_MODEL, W, D_MODEL, C, D_IN2, BL, D_MODEL); }

__global__ __launch_bounds__(256)
void k_gemm_xproj(const short* A, const short* W, float* C)
{ gemm_body<3>(A, D_INNER, W, D_INNER, C, XDBL_N, BL, D_INNER / XPROJ_SPLITS); }

__global__ __launch_bounds__(256)
void k_gemm_outproj(const short* A, const short* W, float* C)
{ gemm_body<0>(A, D_INNER, W, D_INNER, C, D_MODEL, BL, D_INNER / OUT_SPLITS); }

// ---- dt_proj GEMM (fused A-repack, no activation): dt_raw = A @ dtw^T ----
__global__ __launch_bounds__(256)
void k_gemm_dt(const float* __restrict__ Af, const short* __restrict__ W,
               float* __restrict__ C)
{
    __shared__ __align__(16) char smem[65536];
    short* sA = (short*)smem;             // [2][128][64] bf16 = 32 KB
    short* sW = (short*)(smem + 32768);   // [2][128][64] bf16 = 32 KB

    const int tid = threadIdx.x;
    const int w   = tid >> 6;
    const int L   = tid & 63;
    const int bm  = blockIdx.y * 128;
    const int bn  = blockIdx.x * 128;

#pragma unroll
    for (int ci = 0; ci < 8; ci++) {
        const int c_lin = tid * 8 + ci;
        const int r = c_lin >> 4;
        const int c = c_lin & 15;
        const float* src = Af + (size_t)(bm + r) * XDBL_N + c * 8;
        const float4 u = *(const float4*)src;
        const float4 v = *(const float4*)(src + 4);
        const int half = c >> 3, cc = c & 7;
        const int slot = (cc + r) & 7;
        uint4 o;
        o.x = packbf(u.x, u.y); o.y = packbf(u.z, u.w);
        o.z = packbf(v.x, v.y); o.w = packbf(v.z, v.w);
        *(uint4*)&sA[half * 8192 + r * 64 + slot * 8] = o;
    }
    const int rsub = L >> 3;
    const int c8   = (((L & 7) - rsub) & 7) * 8;
#pragma unroll
    for (int half = 0; half < 2; half++)
#pragma unroll
        for (int j = 0; j < 4; j++)
            GLD16(W + (size_t)(bn + w * 32 + j * 8 + rsub) * DT_RANK + half * 64 + c8,
                  &sW[half * 8192 + (w * 32 + j * 8) * 64]);
    __syncthreads();

    const int wm = (w >> 1) * 64;
    const int wn = (w & 1) * 64;
    const int cl = L & 15;
    const int qd = L >> 4;

    f4v acc[4][4];
#pragma unroll
    for (int i = 0; i < 4; i++)
#pragma unroll
        for (int j = 0; j < 4; j++) acc[i][j] = (f4v){0.f, 0.f, 0.f, 0.f};

#pragma unroll
    for (int ks = 0; ks < 4; ks++) {
        const int half = ks >> 1;
        const int sl = (((ks & 1) * 4 + qd + cl) & 7) * 8;
        s8v a[4], b[4];
#pragma unroll
        for (int mt = 0; mt < 4; mt++)
            a[mt] = *(const s8v*)&sA[half * 8192 + (wm + mt * 16 + cl) * 64 + sl];
#pragma unroll
        for (int nt = 0; nt < 4; nt++)
            b[nt] = *(const s8v*)&sW[half * 8192 + (wn + nt * 16 + cl) * 64 + sl];
#pragma unroll
        for (int mt = 0; mt < 4; mt++)
#pragma unroll
            for (int nt = 0; nt < 4; nt++)
                acc[mt][nt] = __builtin_amdgcn_mfma_f32_16x16x32_bf16(
                    a[mt], b[nt], acc[mt][nt], 0, 0, 0);
    }

    __syncthreads();   // staging dead; reuse smem for epilogue
    float (*sC)[132] = (float(*)[132])smem;
#pragma unroll
    for (int half = 0; half < 2; half++) {
        __syncthreads();
        if (wm == half * 64) {
#pragma unroll
            for (int mt = 0; mt < 4; mt++)
#pragma unroll
                for (int nt = 0; nt < 4; nt++)
#pragma unroll
                    for (int r = 0; r < 4; r++)
                        sC[mt * 16 + qd * 4 + r][wn + nt * 16 + cl] =
                            acc[mt][nt][r];
        }
        __syncthreads();
#pragma unroll
        for (int it = 0; it < 8; it++) {
            const int f4  = it * 256 + tid;
            const int row = f4 >> 5;
            const int c4  = (f4 & 31) * 4;
            const float4 v = *(const float4*)&sC[row][c4];
            *(float4*)&C[(size_t)(bm + half * 64 + row) * D_INNER + bn + c4] = v;
        }
    }
}

// ---- out_proj split-K reduce: out = P0 + P1 (float4) ----
__global__ __launch_bounds__(256)
void k_reduce_out(const float* __restrict__ P, float* __restrict__ out)
{
    const int i = blockIdx.x * 256 + threadIdx.x;   // float4 index
    const float4 a = ((const float4*)P)[i];
    const float4 b = ((const float4*)(P + (size_t)BL * D_MODEL))[i];
    ((float4*)out)[i] = make_float4(a.x + b.x, a.y + b.y, a.z + b.z, a.w + b.w);
}

// ---- causal depthwise conv1d (K=4) + SiLU ----
__global__ __launch_bounds__(256)
void k_conv(const short* __restrict__ xz_bf, const float* __restrict__ cw,
            const float* __restrict__ cb, short* __restrict__ x_bf)
{
    const int idx = blockIdx.x * 256 + threadIdx.x;
    const int d  = idx & (D_INNER - 1);
    const int bl = idx >> 12;
    const int l  = bl & (SEQLEN - 1);
    const int b  = bl >> 10;
    const short* xb = xz_bf + (size_t)b * SEQLEN * D_IN2 + d;
    float acc = cb[d];
#pragma unroll
    for (int k = 0; k < D_CONVK; k++) {
        const int ll = l + k - (D_CONVK - 1);
        if (ll >= 0) acc = fmaf(bf2f(xb[(size_t)ll * D_IN2]), cw[d * D_CONVK + k], acc);
    }
    x_bf[idx] = (short)f2bf(silu_f(acc));
}

// ================= chunked selective scan =================
// R6: register-prefetch staging (issue sub+1 global loads under sub's
// t-loop), batched order-preserving prefix reduction in p3, grid-swap so
// long-prefix blocks dispatch early. launch_bounds(256,8) pins VGPR<=64
// to keep 8 blocks/CU while granting prefetch headroom (was VGPR=32).
__global__ __launch_bounds__(256, 8)
void k_scan_p1(const short* __restrict__ x_bf, const float* __restrict__ dtr,
               const float* __restrict__ dtb, const float* __restrict__ xdbl,
               const float* __restrict__ A_log,
               float* __restrict__ h_end, float* __restrict__ Pprod)
{
    const int c   = blockIdx.y;
    const int ch0 = blockIdx.x * 64;
    const int b   = ch0 >> 12;
    const int d0  = ch0 & (D_INNER - 1);
    const int tid = threadIdx.x;
    const int g   = tid >> 2;
    const int q   = tid & 3;
    const int d   = d0 + g;

    const float4 Al = *(const float4*)&A_log[(d << 4) + (q << 2)];
    float An[4] = {-__expf(Al.x), -__expf(Al.y), -__expf(Al.z), -__expf(Al.w)};
    float h[4]  = {0.f, 0.f, 0.f, 0.f};
    float Pp[4] = {1.f, 1.f, 1.f, 1.f};

    __shared__ float s_x [16][68];
    __shared__ float s_dt[16][68];
    __shared__ float s_B [16][20];

    const int lt  = tid >> 4;
    const int ld4 = (tid & 15) * 4;
    const int t2  = tid >> 2;          // B staging row (tid<64)
    const int k4  = (tid & 3) * 4;
    const float4 bb = *(const float4*)&dtb[d0 + ld4];

    short4 rx; float4 rdt, rB;
    {   // preload sub 0
        const size_t bl_ = (size_t)(b * SEQLEN + c * LCHUNK + lt);
        rx  = *(const short4*)&x_bf[bl_ * D_INNER + d0 + ld4];
        rdt = *(const float4*)&dtr [bl_ * D_INNER + d0 + ld4];
        if (tid < 64)
            rB = *(const float4*)&xdbl[(size_t)(b * SEQLEN + c * LCHUNK + t2)
                                       * XDBL_N + DT_RANK + k4];
    }

    for (int sub = 0; sub < LCHUNK / 16; sub++) {
        __syncthreads();
        *(float4*)&s_x [lt][ld4] =
            make_float4(bf2f(rx.x), bf2f(rx.y), bf2f(rx.z), bf2f(rx.w));
        *(float4*)&s_dt[lt][ld4] = make_float4(
            softplus_f(rdt.x + bb.x), softplus_f(rdt.y + bb.y),
            softplus_f(rdt.z + bb.z), softplus_f(rdt.w + bb.w));
        if (tid < 64) *(float4*)&s_B[t2][k4] = rB;
        __syncthreads();
        if (sub + 1 < LCHUNK / 16) {    // prefetch next sub under the t-loop
            const int l0n = c * LCHUNK + (sub + 1) * 16;
            const size_t bl_ = (size_t)(b * SEQLEN + l0n + lt);
            rx  = *(const short4*)&x_bf[bl_ * D_INNER + d0 + ld4];
            rdt = *(const float4*)&dtr [bl_ * D_INNER + d0 + ld4];
            if (tid < 64)
                rB = *(const float4*)&xdbl[(size_t)(b * SEQLEN + l0n + t2)
                                           * XDBL_N + DT_RANK + k4];
        }
#pragma unroll
        for (int t = 0; t < 16; t++) {
            const float xv  = s_x [t][g];
            const float dtv = s_dt[t][g];
            const float4 Bq = *(const float4*)&s_B[t][q * 4];
            const float Bv[4] = {Bq.x, Bq.y, Bq.z, Bq.w};
            const float dtx = dtv * xv;
#pragma unroll
            for (int j = 0; j < 4; j++) {
                const float dA = __expf(dtv * An[j]);
                h[j]  = fmaf(h[j], dA, dtx * Bv[j]);
                Pp[j] *= dA;
            }
        }
    }
    const size_t i0 = (size_t)c * CHW + (((size_t)(b * D_INNER + d)) << 4) + (q << 2);
    *(float4*)&h_end[i0] = make_float4(h[0], h[1], h[2], h[3]);
    *(float4*)&Pprod[i0] = make_float4(Pp[0], Pp[1], Pp[2], Pp[3]);
}

__global__ __launch_bounds__(256, 8)
void k_scan_p3(const short* __restrict__ x_bf, short* __restrict__ y_bf,
               const float* __restrict__ dtr, const float* __restrict__ dtb,
               const float* __restrict__ xdbl,
               const short* __restrict__ xz_bf, const float* __restrict__ A_log,
               const float* __restrict__ Dvec,
               const float* __restrict__ h_end, const float* __restrict__ Pbuf)
{
    const int c   = blockIdx.x;            // grid-swapped: long blocks early
    const int ch0 = blockIdx.y * 64;
    const int b   = ch0 >> 12;
    const int d0  = ch0 & (D_INNER - 1);
    const int tid = threadIdx.x;
    const int g   = tid >> 2;
    const int q   = tid & 3;
    const int d   = d0 + g;

    const float4 Al = *(const float4*)&A_log[(d << 4) + (q << 2)];
    float An[4] = {-__expf(Al.x), -__expf(Al.y), -__expf(Al.z), -__expf(Al.w)};
    const float Dd = Dvec[d];

    // ---- prefix carry: batch-4 loads (independent), fma chain kept in
    //      ascending-j order -> bit-identical to the serial loop ----
    float h[4] = {0.f, 0.f, 0.f, 0.f};
    const size_t base = (((size_t)(b * D_INNER + d)) << 4) + (q << 2);
    {
        int j = 0;
        for (; j + 4 <= c; j += 4) {
            float4 he[4], Pq[4];
#pragma unroll
            for (int u = 0; u < 4; u++) {
                he[u] = *(const float4*)&h_end[(size_t)(j + u) * CHW + base];
                Pq[u] = *(const float4*)&Pbuf [(size_t)(j + u) * CHW + base];
            }
#pragma unroll
            for (int u = 0; u < 4; u++) {
                h[0] = fmaf(Pq[u].x, h[0], he[u].x);
                h[1] = fmaf(Pq[u].y, h[1], he[u].y);
                h[2] = fmaf(Pq[u].z, h[2], he[u].z);
                h[3] = fmaf(Pq[u].w, h[3], he[u].w);
            }
        }
        for (; j < c; j++) {
            const float4 he = *(const float4*)&h_end[(size_t)j * CHW + base];
            const float4 Pq = *(const float4*)&Pbuf [(size_t)j * CHW + base];
            h[0] = fmaf(Pq.x, h[0], he.x);
            h[1] = fmaf(Pq.y, h[1], he.y);
            h[2] = fmaf(Pq.z, h[2], he.z);
            h[3] = fmaf(Pq.w, h[3], he.w);
        }
    }

    __shared__ float s_x [16][68];
    __shared__ float s_dt[16][68];
    __shared__ float s_z [16][68];
    __shared__ float s_B [16][20];
    __shared__ float s_C [16][20];

    const int lt  = tid >> 4;
    const int ld4 = (tid & 15) * 4;
    const int t2  = (tid & 63) >> 2;   // B/C staging row (tid<128)
    const int k4  = (tid & 3) * 4;
    const int offc = (tid < 64) ? 0 : D_STATE;
    const float4 bb = *(const float4*)&dtb[d0 + ld4];

    short4 rx, rz; float4 rdt, rBC;
    {   // preload sub 0
        const size_t bl_ = (size_t)(b * SEQLEN + c * LCHUNK + lt);
        rx  = *(const short4*)&x_bf[bl_ * D_INNER + d0 + ld4];
        rdt = *(const float4*)&dtr [bl_ * D_INNER + d0 + ld4];
        rz  = *(const short4*)&xz_bf[bl_ * D_IN2 + D_INNER + d0 + ld4];
        if (tid < 128)
            rBC = *(const float4*)&xdbl[(size_t)(b * SEQLEN + c * LCHUNK + t2)
                                        * XDBL_N + DT_RANK + offc + k4];
    }

    for (int sub = 0; sub < LCHUNK / 16; sub++) {
        const int l0 = c * LCHUNK + sub * 16;
        __syncthreads();
        *(float4*)&s_x [lt][ld4] =
            make_float4(bf2f(rx.x), bf2f(rx.y), bf2f(rx.z), bf2f(rx.w));
        *(float4*)&s_dt[lt][ld4] = make_float4(
            softplus_f(rdt.x + bb.x), softplus_f(rdt.y + bb.y),
            softplus_f(rdt.z + bb.z), softplus_f(rdt.w + bb.w));
        *(float4*)&s_z [lt][ld4] =
            make_float4(bf2f(rz.x), bf2f(rz.y), bf2f(rz.z), bf2f(rz.w));
        if (tid < 128) {
            if (tid < 64) *(float4*)&s_B[t2][k4] = rBC;
            else          *(float4*)&s_C[t2][k4] = rBC;
        }
        __syncthreads();
        if (sub + 1 < LCHUNK / 16) {    // prefetch next sub under the t-loop
            const int l0n = l0 + 16;
            const size_t bl_ = (size_t)(b * SEQLEN + l0n + lt);
            rx  = *(const short4*)&x_bf[bl_ * D_INNER + d0 + ld4];
            rdt = *(const float4*)&dtr [bl_ * D_INNER + d0 + ld4];
            rz  = *(const short4*)&xz_bf[bl_ * D_IN2 + D_INNER + d0 + ld4];
            if (tid < 128)
                rBC = *(const float4*)&xdbl[(size_t)(b * SEQLEN + l0n + t2)
                                            * XDBL_N + DT_RANK + offc + k4];
        }
        const size_t orow = (size_t)(b * SEQLEN + l0);
#pragma unroll
        for (int t = 0; t < 16; t++) {
            const float xv  = s_x [t][g];
            const float dtv = s_dt[t][g];
            const float4 Bq = *(const float4*)&s_B[t][q * 4];
            const float4 Cq = *(const float4*)&s_C[t][q * 4];
            const float Bv[4] = {Bq.x, Bq.y, Bq.z, Bq.w};
            const float Cv[4] = {Cq.x, Cq.y, Cq.z, Cq.w};
            const float dtx = dtv * xv;
            float p = 0.f;
#pragma unroll
            for (int j = 0; j < 4; j++) {
                const float dA = __expf(dtv * An[j]);
                h[j] = fmaf(h[j], dA, dtx * Bv[j]);
                p = fmaf(h[j], Cv[j], p);
            }
            p = quad_sum(p);
            if (q == 0) {
                const float yv = fmaf(xv, Dd, p) * silu_f(s_z[t][g]);
                y_bf[(orow + t) * D_INNER + d] = (short)f2bf(yv);
            }
        }
    }
}

extern "C" void kernel_launch(void* const* d_in, const int* in_sizes, int n_in,
                              void* d_out, int out_size, void* d_ws, size_t ws_size,
                              hipStream_t stream)
{
    const float* hidden     = (const float*)d_in[0];
    const float* in_proj_w  = (const float*)d_in[1];
    const float* conv_w     = (const float*)d_in[2];
    const float* conv_b     = (const float*)d_in[3];
    const float* x_proj_w   = (const float*)d_in[4];
    const float* dt_proj_w  = (const float*)d_in[5];
    const float* dt_proj_b  = (const float*)d_in[6];
    const float* A_log      = (const float*)d_in[7];
    const float* Dvec       = (const float*)d_in[8];
    const float* out_proj_w = (const float*)d_in[9];
    float* out = (float*)d_out;

    // ---- workspace layout (stream-ordered aliasing, ~140.3 MB) ----
    const size_t MB = 1ull << 20;
    char* ws = (char*)d_ws;
    short* xz_bf   = (short*)(ws);                  // [0,32)   bf16 [BL,8192]
    short* x_bf    = (short*)(ws + 32 * MB);        // [32,48)  bf16 [BL,4096]
    short* ipw_bf  = (short*)(ws + 48 * MB);        // [48,80)  dead after in_proj
    short* y_bf    = (short*)(ws + 48 * MB);        // alias (phase3)
    float* h_end   = (float*)(ws + 64 * MB);        // [64,72)  alias (phase1)
    float* Pbuf    = (float*)(ws + 72 * MB);        // [72,80)  alias (phase1)
    short* hid_bf  = (short*)(ws + 80 * MB);        // [80,88)  dead after in_proj
    short* opw_bf  = (short*)(ws + 88 * MB);        // [88,104)
    float* dt_raw  = (float*)(ws + 104 * MB);       // [104,136) live thru p3
    float* op_part = (float*)(ws + 104 * MB);       // alias: outproj partials (after p3)
    short* xpw_bf  = (short*)(ws + 136 * MB);       // [136,138)
    short* dtw_bf  = (short*)(ws + 138 * MB);       // [138,139)
    float* xdbl_f  = (float*)(ws + 139 * MB);       // 1.25 MB, atomic target

    const dim3 blk(256);

    // 0) fused casts + zero-fills
    k_cast_all<<<dim3(NB_HID + NB_IPW + NB_XPW + NB_XPWZ + NB_DTW + NB_OPW + NB_XDBLZ),
                blk, 0, stream>>>(
        hidden, (uint32_t*)hid_bf, in_proj_w, (uint32_t*)ipw_bf,
        x_proj_w, (uint32_t*)xpw_bf, dt_proj_w, (uint32_t*)dtw_bf,
        out_proj_w, (uint32_t*)opw_bf,
        (uint32_t*)(xpw_bf + (size_t)XDBL_N * D_INNER),
        (uint32_t*)xdbl_f);

    // 1) in_proj -> xz_bf (bf16 coalesced epilogue)
    k_gemm_inproj<<<dim3(D_IN2 / 128, BL / 128, 1), blk, 0, stream>>>(
        hid_bf, ipw_bf, xz_bf);

    // 2) conv + SiLU -> x_bf
    k_conv<<<dim3((BL * D_INNER) / 256), blk, 0, stream>>>(
        xz_bf, conv_w, conv_b, x_bf);

    // 3) x_proj split-K=8: atomicAdd into xdbl_f
    k_gemm_xproj<<<dim3(XPW_NPAD / 128, BL / 128, XPROJ_SPLITS), blk, 0, stream>>>(
        x_bf, xpw_bf, xdbl_f);

    // 4) dt_proj GEMM (fused A-repack, no activation) -> dt_raw;
    //    bias+softplus are applied at the scans' dt-load.
    k_gemm_dt<<<dim3(D_INNER / 128, BL / 128), blk, 0, stream>>>(
        xdbl_f, dtw_bf, dt_raw);

    // 5) chunked selective scan (p3 grid-swapped: c = blockIdx.x)
    k_scan_p1<<<dim3(BATCH * D_INNER / 64, NCHUNK - 1), blk, 0, stream>>>(
        x_bf, dt_raw, dt_proj_b, xdbl_f, A_log, h_end, Pbuf);
    k_scan_p3<<<dim3(NCHUNK, BATCH * D_INNER / 64), blk, 0, stream>>>(
        x_bf, y_bf, dt_raw, dt_proj_b, xdbl_f, xz_bf, A_log, Dvec, h_end, Pbuf);

    // 6) out_proj split-K=2 -> partials (coalesced), then reduce into d_out
    k_gemm_outproj<<<dim3(D_MODEL / 128, BL / 128, OUT_SPLITS), blk, 0, stream>>>(
        y_bf, opw_bf, op_part);
    k_reduce_out<<<dim3(BL * D_MODEL / 4 / 256), blk, 0, stream>>>(op_part, out);
}

// Round 7
// 451.835 us; speedup vs baseline: 1.0765x; 1.0765x over previous
//
#include <hip/hip_runtime.h>
#include <cstdint>
#include <cstddef>

// ---- problem constants ----
#define D_MODEL 2048
#define D_INNER 4096
#define D_IN2   8192
#define D_STATE 16
#define D_CONVK 4
#define DT_RANK 128
#define BATCH   2
#define SEQLEN  1024
#define BL      (BATCH*SEQLEN)
#define XDBL_N  (DT_RANK + 2*D_STATE)   // 160
#define XPW_NPAD 256
#define XPROJ_SPLITS 8
#define OUT_SPLITS 2

// chunked-scan constants
#define NCHUNK  16
#define LCHUNK  (SEQLEN/NCHUNK)         // 64
#define CHW     (BATCH*D_INNER*D_STATE) // 131072

// fused-cast segment block counts (256 thr/block, 1 uint4 out/thread)
#define NB_HID   2048
#define NB_IPW   8192
#define NB_XPW   320
#define NB_XPWZ  192
#define NB_DTW   256
#define NB_OPW   4096
#define NB_XDBLZ 320

typedef short  s8v  __attribute__((ext_vector_type(8)));
typedef float  f4v  __attribute__((ext_vector_type(4)));

__device__ __forceinline__ float softplus_f(float v) {
    return (v > 20.f) ? v : log1pf(__expf(v));
}
__device__ __forceinline__ float silu_f(float v) {
    return v / (1.f + __expf(-v));
}
// native 2^x (v_exp_f32): __expf emits mul-by-log2e + v_exp; folding log2e
// into the precomputed A coefficient saves the mul in the 87%-VALU t-loop.
__device__ __forceinline__ float exp2_f(float x) {
    float r; asm("v_exp_f32 %0, %1" : "=v"(r) : "v"(x)); return r;
}
__device__ __forceinline__ float bf2f(short s) {
    return __uint_as_float(((uint32_t)(uint16_t)s) << 16);
}
__device__ __forceinline__ uint16_t f2bf(float f) {
    uint32_t u = __float_as_uint(f);
    return (uint16_t)((u + 0x7FFFu + ((u >> 16) & 1u)) >> 16);
}
__device__ __forceinline__ uint32_t packbf(float lo, float hi) {
    return ((uint32_t)f2bf(hi) << 16) | (uint32_t)f2bf(lo);
}
__device__ __forceinline__ float quad_sum(float p) {
    p += __int_as_float(__builtin_amdgcn_update_dpp(
            0, __float_as_int(p), 0xB1, 0xF, 0xF, true));
    p += __int_as_float(__builtin_amdgcn_update_dpp(
            0, __float_as_int(p), 0x4E, 0xF, 0xF, true));
    return p;
}

#define GLD16(gp, lp)                                                          \
    __builtin_amdgcn_global_load_lds(                                          \
        (const __attribute__((address_space(1))) void*)(gp),                   \
        (__attribute__((address_space(3))) void*)(lp), 16, 0, 0)

// ---- fused: all fp32->bf16 casts + zero-fills, one dispatch ----
__global__ __launch_bounds__(256)
void k_cast_all(const float* __restrict__ s0, uint32_t* __restrict__ d0,
                const float* __restrict__ s1, uint32_t* __restrict__ d1,
                const float* __restrict__ s2, uint32_t* __restrict__ d2,
                const float* __restrict__ s3, uint32_t* __restrict__ d3,
                const float* __restrict__ s4, uint32_t* __restrict__ d4,
                uint32_t* __restrict__ z0, uint32_t* __restrict__ z1)
{
    int blk = blockIdx.x;
    const float* src = nullptr; uint32_t* dst; int base; int zero = 0;
    if      (blk < NB_HID) { src = s0; dst = d0; base = blk; }
    else if ((blk -= NB_HID)  < NB_IPW)  { src = s1; dst = d1; base = blk; }
    else if ((blk -= NB_IPW)  < NB_XPW)  { src = s2; dst = d2; base = blk; }
    else if ((blk -= NB_XPW)  < NB_XPWZ) { dst = z0; base = blk; zero = 1; }
    else if ((blk -= NB_XPWZ) < NB_DTW)  { src = s3; dst = d3; base = blk; }
    else if ((blk -= NB_DTW)  < NB_OPW)  { src = s4; dst = d4; base = blk; }
    else                                 { dst = z1; base = blk - NB_OPW; zero = 1; }
    const int i = base * 256 + threadIdx.x;
    if (zero) { ((uint4*)dst)[i] = make_uint4(0u, 0u, 0u, 0u); return; }
    const float4 a = ((const float4*)src)[i * 2];
    const float4 b = ((const float4*)src)[i * 2 + 1];
    uint4 o;
    o.x = packbf(a.x, a.y); o.y = packbf(a.z, a.w);
    o.z = packbf(b.x, b.y); o.w = packbf(b.z, b.w);
    ((uint4*)dst)[i] = o;
}

// ---- bf16 MFMA GEMM body: C[m,n] = sum_k A[m,k]*W[n,k], BK=64, swizzled ----
// EPI: 0 = fp32 LDS-coalesced store to slice blockIdx.z,
//      2 = bf16 LDS-coalesced store,
//      3 = fp32 atomicAdd (xproj, tiny output).
template<int EPI>
__device__ __forceinline__
void gemm_body(const short* __restrict__ A, int lda,
               const short* __restrict__ W, int ldw,
               void* __restrict__ Cv, int ldc, int M, int kchunk)
{
    constexpr int SMEM_BYTES = (EPI == 2) ? 34816 : (EPI == 0) ? 33792 : 32768;
    __shared__ __align__(16) char smem[SMEM_BYTES];
    short* sA = (short*)smem;             // 128x64 bf16 = 16 KB
    short* sW = (short*)(smem + 16384);   // 128x64 bf16 = 16 KB

    const int tid = threadIdx.x;
    const int w   = tid >> 6;
    const int L   = tid & 63;
    const int bm  = blockIdx.y * 128;
    const int bn  = blockIdx.x * 128;
    const int k0  = blockIdx.z * kchunk;

    const int rsub = L >> 3;
    const int c8   = (((L & 7) - rsub) & 7) * 8;
    const short* Ag[4]; const short* Wg[4];
#pragma unroll
    for (int j = 0; j < 4; j++) {
        Ag[j] = A + (size_t)(bm + w * 32 + j * 8 + rsub) * lda + c8 + k0;
        Wg[j] = W + (size_t)(bn + w * 32 + j * 8 + rsub) * ldw + c8 + k0;
    }

    const int wm = (w >> 1) * 64;
    const int wn = (w & 1) * 64;
    const int cl = L & 15;
    const int qd = L >> 4;

    f4v acc[4][4];
#pragma unroll
    for (int i = 0; i < 4; i++)
#pragma unroll
        for (int j = 0; j < 4; j++) acc[i][j] = (f4v){0.f, 0.f, 0.f, 0.f};

    for (int k = 0; k < kchunk; k += 64) {
#pragma unroll
        for (int j = 0; j < 4; j++)
            GLD16(Ag[j] + k, &sA[(w * 32 + j * 8) * 64]);
#pragma unroll
        for (int j = 0; j < 4; j++)
            GLD16(Wg[j] + k, &sW[(w * 32 + j * 8) * 64]);
        __syncthreads();
#pragma unroll
        for (int kk = 0; kk < 2; kk++) {
            const int sl = ((kk * 4 + qd + cl) & 7) * 8;
            s8v a[4], b[4];
#pragma unroll
            for (int mt = 0; mt < 4; mt++)
                a[mt] = *(const s8v*)&sA[(wm + mt * 16 + cl) * 64 + sl];
#pragma unroll
            for (int nt = 0; nt < 4; nt++)
                b[nt] = *(const s8v*)&sW[(wn + nt * 16 + cl) * 64 + sl];
#pragma unroll
            for (int mt = 0; mt < 4; mt++)
#pragma unroll
                for (int nt = 0; nt < 4; nt++)
                    acc[mt][nt] = __builtin_amdgcn_mfma_f32_16x16x32_bf16(
                        a[mt], b[nt], acc[mt][nt], 0, 0, 0);
        }
        __syncthreads();   // also fences staging before epilogue smem reuse
    }

    if constexpr (EPI == 2) {
        ushort (*sC)[136] = (ushort(*)[136])smem;
        short* Cs = (short*)Cv;
#pragma unroll
        for (int mt = 0; mt < 4; mt++)
#pragma unroll
            for (int nt = 0; nt < 4; nt++)
#pragma unroll
                for (int r = 0; r < 4; r++)
                    sC[wm + mt * 16 + qd * 4 + r][wn + nt * 16 + cl] =
                        (ushort)f2bf(acc[mt][nt][r]);
        __syncthreads();
#pragma unroll
        for (int it = 0; it < 8; it++) {
            const int idx = it * 256 + tid;
            const int row = idx >> 4;          // 128 rows
            const int c8s = (idx & 15) * 8;    // 16B chunks, 256B/row
            *(uint4*)&Cs[(size_t)(bm + row) * ldc + bn + c8s] =
                *(const uint4*)&sC[row][c8s];
        }
    } else if constexpr (EPI == 0) {
        float (*sC)[132] = (float(*)[132])smem;
        float* Cf = (float*)Cv + (size_t)blockIdx.z * M * ldc;
#pragma unroll
        for (int half = 0; half < 2; half++) {
            __syncthreads();
            if (wm == half * 64) {
#pragma unroll
                for (int mt = 0; mt < 4; mt++)
#pragma unroll
                    for (int nt = 0; nt < 4; nt++)
#pragma unroll
                        for (int r = 0; r < 4; r++)
                            sC[mt * 16 + qd * 4 + r][wn + nt * 16 + cl] =
                                acc[mt][nt][r];
            }
            __syncthreads();
#pragma unroll
            for (int it = 0; it < 8; it++) {
                const int f4  = it * 256 + tid;
                const int row = f4 >> 5;
                const int c4  = (f4 & 31) * 4;
                const float4 v = *(const float4*)&sC[row][c4];
                *(float4*)&Cf[(size_t)(bm + half * 64 + row) * ldc + bn + c4] = v;
            }
        }
    } else {
        float* Cf = (float*)Cv;
#pragma unroll
        for (int mt = 0; mt < 4; mt++) {
            const int row0 = bm + wm + mt * 16 + qd * 4;
#pragma unroll
            for (int nt = 0; nt < 4; nt++) {
                const int col = bn + wn + nt * 16 + cl;
                if (col >= XDBL_N) continue;
#pragma unroll
                for (int r = 0; r < 4; r++)
                    atomicAdd(&Cf[(size_t)(row0 + r) * ldc + col], acc[mt][nt][r]);
            }
        }
    }
}

// named entry points (profiling visibility)
__global__ __launch_bounds__(256)
void k_gemm_inproj(const short* A, const short* W, short* C)
{ gemm_body<2>(A, D_MODEL, W, D_MODEL, C, D_IN2, BL, D_MODEL); }

__global__ __launch_bounds__(256)
void k_gemm_xproj(const short* A, const short* W, float* C)
{ gemm_body<3>(A, D_INNER, W, D_INNER, C, XDBL_N, BL, D_INNER / XPROJ_SPLITS); }

__global__ __launch_bounds__(256)
void k_gemm_outproj(const short* A, const short* W, float* C)
{ gemm_body<0>(A, D_INNER, W, D_INNER, C, D_MODEL, BL, D_INNER / OUT_SPLITS); }

// ---- dt_proj GEMM (fused A-repack, no activation): dt_raw = A @ dtw^T ----
__global__ __launch_bounds__(256)
void k_gemm_dt(const float* __restrict__ Af, const short* __restrict__ W,
               float* __restrict__ C)
{
    __shared__ __align__(16) char smem[65536];
    short* sA = (short*)smem;             // [2][128][64] bf16 = 32 KB
    short* sW = (short*)(smem + 32768);   // [2][128][64] bf16 = 32 KB

    const int tid = threadIdx.x;
    const int w   = tid >> 6;
    const int L   = tid & 63;
    const int bm  = blockIdx.y * 128;
    const int bn  = blockIdx.x * 128;

#pragma unroll
    for (int ci = 0; ci < 8; ci++) {
        const int c_lin = tid * 8 + ci;
        const int r = c_lin >> 4;
        const int c = c_lin & 15;
        const float* src = Af + (size_t)(bm + r) * XDBL_N + c * 8;
        const float4 u = *(const float4*)src;
        const float4 v = *(const float4*)(src + 4);
        const int half = c >> 3, cc = c & 7;
        const int slot = (cc + r) & 7;
        uint4 o;
        o.x = packbf(u.x, u.y); o.y = packbf(u.z, u.w);
        o.z = packbf(v.x, v.y); o.w = packbf(v.z, v.w);
        *(uint4*)&sA[half * 8192 + r * 64 + slot * 8] = o;
    }
    const int rsub = L >> 3;
    const int c8   = (((L & 7) - rsub) & 7) * 8;
#pragma unroll
    for (int half = 0; half < 2; half++)
#pragma unroll
        for (int j = 0; j < 4; j++)
            GLD16(W + (size_t)(bn + w * 32 + j * 8 + rsub) * DT_RANK + half * 64 + c8,
                  &sW[half * 8192 + (w * 32 + j * 8) * 64]);
    __syncthreads();

    const int wm = (w >> 1) * 64;
    const int wn = (w & 1) * 64;
    const int cl = L & 15;
    const int qd = L >> 4;

    f4v acc[4][4];
#pragma unroll
    for (int i = 0; i < 4; i++)
#pragma unroll
        for (int j = 0; j < 4; j++) acc[i][j] = (f4v){0.f, 0.f, 0.f, 0.f};

#pragma unroll
    for (int ks = 0; ks < 4; ks++) {
        const int half = ks >> 1;
        const int sl = (((ks & 1) * 4 + qd + cl) & 7) * 8;
        s8v a[4], b[4];
#pragma unroll
        for (int mt = 0; mt < 4; mt++)
            a[mt] = *(const s8v*)&sA[half * 8192 + (wm + mt * 16 + cl) * 64 + sl];
#pragma unroll
        for (int nt = 0; nt < 4; nt++)
            b[nt] = *(const s8v*)&sW[half * 8192 + (wn + nt * 16 + cl) * 64 + sl];
#pragma unroll
        for (int mt = 0; mt < 4; mt++)
#pragma unroll
            for (int nt = 0; nt < 4; nt++)
                acc[mt][nt] = __builtin_amdgcn_mfma_f32_16x16x32_bf16(
                    a[mt], b[nt], acc[mt][nt], 0, 0, 0);
    }

    __syncthreads();   // staging dead; reuse smem for epilogue
    float (*sC)[132] = (float(*)[132])smem;
#pragma unroll
    for (int half = 0; half < 2; half++) {
        __syncthreads();
        if (wm == half * 64) {
#pragma unroll
            for (int mt = 0; mt < 4; mt++)
#pragma unroll
                for (int nt = 0; nt < 4; nt++)
#pragma unroll
                    for (int r = 0; r < 4; r++)
                        sC[mt * 16 + qd * 4 + r][wn + nt * 16 + cl] =
                            acc[mt][nt][r];
        }
        __syncthreads();
#pragma unroll
        for (int it = 0; it < 8; it++) {
            const int f4  = it * 256 + tid;
            const int row = f4 >> 5;
            const int c4  = (f4 & 31) * 4;
            const float4 v = *(const float4*)&sC[row][c4];
            *(float4*)&C[(size_t)(bm + half * 64 + row) * D_INNER + bn + c4] = v;
        }
    }
}

// ---- out_proj split-K reduce: out = P0 + P1 (float4) ----
__global__ __launch_bounds__(256)
void k_reduce_out(const float* __restrict__ P, float* __restrict__ out)
{
    const int i = blockIdx.x * 256 + threadIdx.x;   // float4 index
    const float4 a = ((const float4*)P)[i];
    const float4 b = ((const float4*)(P + (size_t)BL * D_MODEL))[i];
    ((float4*)out)[i] = make_float4(a.x + b.x, a.y + b.y, a.z + b.z, a.w + b.w);
}

// ---- causal depthwise conv1d (K=4) + SiLU ----
__global__ __launch_bounds__(256)
void k_conv(const short* __restrict__ xz_bf, const float* __restrict__ cw,
            const float* __restrict__ cb, short* __restrict__ x_bf)
{
    const int idx = blockIdx.x * 256 + threadIdx.x;
    const int d  = idx & (D_INNER - 1);
    const int bl = idx >> 12;
    const int l  = bl & (SEQLEN - 1);
    const int b  = bl >> 10;
    const short* xb = xz_bf + (size_t)b * SEQLEN * D_IN2 + d;
    float acc = cb[d];
#pragma unroll
    for (int k = 0; k < D_CONVK; k++) {
        const int ll = l + k - (D_CONVK - 1);
        if (ll >= 0) acc = fmaf(bf2f(xb[(size_t)ll * D_IN2]), cw[d * D_CONVK + k], acc);
    }
    x_bf[idx] = (short)f2bf(silu_f(acc));
}

// ================= chunked selective scan =================
// R7: round-5 structure restored (c = blockIdx.y for p3 -> L2 locality:
// R6's grid swap doubled FETCH 42->89 MB; reg-prefetch was compiler-defeated
// at VGPR=32). New: VALU cuts for the measured 87%-VALUBusy t-loop:
//   - An pre-scaled by log2e, dA = v_exp_f32 directly (saves the hidden
//     mul-by-log2e __expf emits, 4 ops/t)
//   - silu(z) computed at staging, not per-t under exec-mask (p3)
__global__ __launch_bounds__(256)
void k_scan_p1(const short* __restrict__ x_bf, const float* __restrict__ dtr,
               const float* __restrict__ dtb, const float* __restrict__ xdbl,
               const float* __restrict__ A_log,
               float* __restrict__ h_end, float* __restrict__ Pprod)
{
    const int c   = blockIdx.y;
    const int ch0 = blockIdx.x * 64;
    const int b   = ch0 >> 12;
    const int d0  = ch0 & (D_INNER - 1);
    const int tid = threadIdx.x;
    const int g   = tid >> 2;
    const int q   = tid & 3;
    const int d   = d0 + g;

    const float LOG2E = 1.44269504f;
    const float4 Al = *(const float4*)&A_log[(d << 4) + (q << 2)];
    float An[4] = {-__expf(Al.x) * LOG2E, -__expf(Al.y) * LOG2E,
                   -__expf(Al.z) * LOG2E, -__expf(Al.w) * LOG2E};
    float h[4]  = {0.f, 0.f, 0.f, 0.f};
    float Pp[4] = {1.f, 1.f, 1.f, 1.f};

    __shared__ float s_x [16][68];
    __shared__ float s_dt[16][68];
    __shared__ float s_B [16][20];

    const int lt  = tid >> 4;
    const int ld4 = (tid & 15) * 4;
    const float4 bb = *(const float4*)&dtb[d0 + ld4];

    for (int sub = 0; sub < LCHUNK / 16; sub++) {
        const int l0 = c * LCHUNK + sub * 16;
        const size_t bl = (size_t)(b * SEQLEN + l0 + lt);
        __syncthreads();
        {
            const short4 sx = *(const short4*)&x_bf[bl * D_INNER + d0 + ld4];
            const float4 dv = *(const float4*)&dtr[bl * D_INNER + d0 + ld4];
            *(float4*)&s_x [lt][ld4] =
                make_float4(bf2f(sx.x), bf2f(sx.y), bf2f(sx.z), bf2f(sx.w));
            *(float4*)&s_dt[lt][ld4] = make_float4(
                softplus_f(dv.x + bb.x), softplus_f(dv.y + bb.y),
                softplus_f(dv.z + bb.z), softplus_f(dv.w + bb.w));
            if (tid < 64) {
                const int t2 = tid >> 2, k = (tid & 3) * 4;
                const size_t bl2 = (size_t)(b * SEQLEN + l0 + t2);
                *(float4*)&s_B[t2][k] =
                    *(const float4*)&xdbl[bl2 * XDBL_N + DT_RANK + k];
            }
        }
        __syncthreads();
#pragma unroll
        for (int t = 0; t < 16; t++) {
            const float xv  = s_x [t][g];
            const float dtv = s_dt[t][g];
            const float4 Bq = *(const float4*)&s_B[t][q * 4];
            const float Bv[4] = {Bq.x, Bq.y, Bq.z, Bq.w};
            const float dtx = dtv * xv;
#pragma unroll
            for (int j = 0; j < 4; j++) {
                const float dA = exp2_f(dtv * An[j]);
                h[j]  = fmaf(h[j], dA, dtx * Bv[j]);
                Pp[j] *= dA;
            }
        }
    }
    const size_t i0 = (size_t)c * CHW + (((size_t)(b * D_INNER + d)) << 4) + (q << 2);
    *(float4*)&h_end[i0] = make_float4(h[0], h[1], h[2], h[3]);
    *(float4*)&Pprod[i0] = make_float4(Pp[0], Pp[1], Pp[2], Pp[3]);
}

__global__ __launch_bounds__(256)
void k_scan_p3(const short* __restrict__ x_bf, short* __restrict__ y_bf,
               const float* __restrict__ dtr, const float* __restrict__ dtb,
               const float* __restrict__ xdbl,
               const short* __restrict__ xz_bf, const float* __restrict__ A_log,
               const float* __restrict__ Dvec,
               const float* __restrict__ h_end, const float* __restrict__ Pbuf)
{
    const int c   = blockIdx.y;
    const int ch0 = blockIdx.x * 64;
    const int b   = ch0 >> 12;
    const int d0  = ch0 & (D_INNER - 1);
    const int tid = threadIdx.x;
    const int g   = tid >> 2;
    const int q   = tid & 3;
    const int d   = d0 + g;

    const float LOG2E = 1.44269504f;
    const float4 Al = *(const float4*)&A_log[(d << 4) + (q << 2)];
    float An[4] = {-__expf(Al.x) * LOG2E, -__expf(Al.y) * LOG2E,
                   -__expf(Al.z) * LOG2E, -__expf(Al.w) * LOG2E};
    const float Dd = Dvec[d];

    // ---- prefix carry: batch-4 loads (independent), fma chain kept in
    //      ascending-j order -> bit-identical to the serial loop ----
    float h[4] = {0.f, 0.f, 0.f, 0.f};
    const size_t base = (((size_t)(b * D_INNER + d)) << 4) + (q << 2);
    {
        int j = 0;
        for (; j + 4 <= c; j += 4) {
            float4 he[4], Pq[4];
#pragma unroll
            for (int u = 0; u < 4; u++) {
                he[u] = *(const float4*)&h_end[(size_t)(j + u) * CHW + base];
                Pq[u] = *(const float4*)&Pbuf [(size_t)(j + u) * CHW + base];
            }
#pragma unroll
            for (int u = 0; u < 4; u++) {
                h[0] = fmaf(Pq[u].x, h[0], he[u].x);
                h[1] = fmaf(Pq[u].y, h[1], he[u].y);
                h[2] = fmaf(Pq[u].z, h[2], he[u].z);
                h[3] = fmaf(Pq[u].w, h[3], he[u].w);
            }
        }
        for (; j < c; j++) {
            const float4 he = *(const float4*)&h_end[(size_t)j * CHW + base];
            const float4 Pq = *(const float4*)&Pbuf [(size_t)j * CHW + base];
            h[0] = fmaf(Pq.x, h[0], he.x);
            h[1] = fmaf(Pq.y, h[1], he.y);
            h[2] = fmaf(Pq.z, h[2], he.z);
            h[3] = fmaf(Pq.w, h[3], he.w);
        }
    }

    __shared__ float s_x [16][68];
    __shared__ float s_dt[16][68];
    __shared__ float s_z [16][68];   // holds silu(z), precomputed at staging
    __shared__ float s_B [16][20];
    __shared__ float s_C [16][20];

    const int lt  = tid >> 4;
    const int ld4 = (tid & 15) * 4;
    const float4 bb = *(const float4*)&dtb[d0 + ld4];

    for (int sub = 0; sub < LCHUNK / 16; sub++) {
        const int l0 = c * LCHUNK + sub * 16;
        const size_t bl = (size_t)(b * SEQLEN + l0 + lt);
        __syncthreads();
        {
            const short4 sx = *(const short4*)&x_bf[bl * D_INNER + d0 + ld4];
            const float4 dv = *(const float4*)&dtr[bl * D_INNER + d0 + ld4];
            const short4 zv = *(const short4*)&xz_bf[bl * D_IN2 + D_INNER + d0 + ld4];
            *(float4*)&s_x [lt][ld4] =
                make_float4(bf2f(sx.x), bf2f(sx.y), bf2f(sx.z), bf2f(sx.w));
            *(float4*)&s_dt[lt][ld4] = make_float4(
                softplus_f(dv.x + bb.x), softplus_f(dv.y + bb.y),
                softplus_f(dv.z + bb.z), softplus_f(dv.w + bb.w));
            *(float4*)&s_z [lt][ld4] = make_float4(
                silu_f(bf2f(zv.x)), silu_f(bf2f(zv.y)),
                silu_f(bf2f(zv.z)), silu_f(bf2f(zv.w)));
            if (tid < 128) {
                const int t2 = (tid & 63) >> 2, k = (tid & 3) * 4;
                const size_t bl2 = (size_t)(b * SEQLEN + l0 + t2);
                const int off = (tid < 64) ? 0 : D_STATE;
                const float4 v =
                    *(const float4*)&xdbl[bl2 * XDBL_N + DT_RANK + off + k];
                if (tid < 64) *(float4*)&s_B[t2][k] = v;
                else          *(float4*)&s_C[t2][k] = v;
            }
        }
        __syncthreads();
        const size_t orow = (size_t)(b * SEQLEN + l0);
#pragma unroll
        for (int t = 0; t < 16; t++) {
            const float xv  = s_x [t][g];
            const float dtv = s_dt[t][g];
            const float4 Bq = *(const float4*)&s_B[t][q * 4];
            const float4 Cq = *(const float4*)&s_C[t][q * 4];
            const float Bv[4] = {Bq.x, Bq.y, Bq.z, Bq.w};
            const float Cv[4] = {Cq.x, Cq.y, Cq.z, Cq.w};
            const float dtx = dtv * xv;
            float p = 0.f;
#pragma unroll
            for (int j = 0; j < 4; j++) {
                const float dA = exp2_f(dtv * An[j]);
                h[j] = fmaf(h[j], dA, dtx * Bv[j]);
                p = fmaf(h[j], Cv[j], p);
            }
            p = quad_sum(p);
            if (q == 0) {
                const float yv = fmaf(xv, Dd, p) * s_z[t][g];
                y_bf[(orow + t) * D_INNER + d] = (short)f2bf(yv);
            }
        }
    }
}

extern "C" void kernel_launch(void* const* d_in, const int* in_sizes, int n_in,
                              void* d_out, int out_size, void* d_ws, size_t ws_size,
                              hipStream_t stream)
{
    const float* hidden     = (const float*)d_in[0];
    const float* in_proj_w  = (const float*)d_in[1];
    const float* conv_w     = (const float*)d_in[2];
    const float* conv_b     = (const float*)d_in[3];
    const float* x_proj_w   = (const float*)d_in[4];
    const float* dt_proj_w  = (const float*)d_in[5];
    const float* dt_proj_b  = (const float*)d_in[6];
    const float* A_log      = (const float*)d_in[7];
    const float* Dvec       = (const float*)d_in[8];
    const float* out_proj_w = (const float*)d_in[9];
    float* out = (float*)d_out;

    // ---- workspace layout (stream-ordered aliasing, ~140.3 MB) ----
    const size_t MB = 1ull << 20;
    char* ws = (char*)d_ws;
    short* xz_bf   = (short*)(ws);                  // [0,32)   bf16 [BL,8192]
    short* x_bf    = (short*)(ws + 32 * MB);        // [32,48)  bf16 [BL,4096]
    short* ipw_bf  = (short*)(ws + 48 * MB);        // [48,80)  dead after in_proj
    short* y_bf    = (short*)(ws + 48 * MB);        // alias (phase3)
    float* h_end   = (float*)(ws + 64 * MB);        // [64,72)  alias (phase1)
    float* Pbuf    = (float*)(ws + 72 * MB);        // [72,80)  alias (phase1)
    short* hid_bf  = (short*)(ws + 80 * MB);        // [80,88)  dead after in_proj
    short* opw_bf  = (short*)(ws + 88 * MB);        // [88,104)
    float* dt_raw  = (float*)(ws + 104 * MB);       // [104,136) live thru p3
    float* op_part = (float*)(ws + 104 * MB);       // alias: outproj partials (after p3)
    short* xpw_bf  = (short*)(ws + 136 * MB);       // [136,138)
    short* dtw_bf  = (short*)(ws + 138 * MB);       // [138,139)
    float* xdbl_f  = (float*)(ws + 139 * MB);       // 1.25 MB, atomic target

    const dim3 blk(256);

    // 0) fused casts + zero-fills
    k_cast_all<<<dim3(NB_HID + NB_IPW + NB_XPW + NB_XPWZ + NB_DTW + NB_OPW + NB_XDBLZ),
                blk, 0, stream>>>(
        hidden, (uint32_t*)hid_bf, in_proj_w, (uint32_t*)ipw_bf,
        x_proj_w, (uint32_t*)xpw_bf, dt_proj_w, (uint32_t*)dtw_bf,
        out_proj_w, (uint32_t*)opw_bf,
        (uint32_t*)(xpw_bf + (size_t)XDBL_N * D_INNER),
        (uint32_t*)xdbl_f);

    // 1) in_proj -> xz_bf (bf16 coalesced epilogue)
    k_gemm_inproj<<<dim3(D_IN2 / 128, BL / 128, 1), blk, 0, stream>>>(
        hid_bf, ipw_bf, xz_bf);

    // 2) conv + SiLU -> x_bf
    k_conv<<<dim3((BL * D_INNER) / 256), blk, 0, stream>>>(
        xz_bf, conv_w, conv_b, x_bf);

    // 3) x_proj split-K=8: atomicAdd into xdbl_f
    k_gemm_xproj<<<dim3(XPW_NPAD / 128, BL / 128, XPROJ_SPLITS), blk, 0, stream>>>(
        x_bf, xpw_bf, xdbl_f);

    // 4) dt_proj GEMM (fused A-repack, no activation) -> dt_raw;
    //    bias+softplus are applied at the scans' dt-load.
    k_gemm_dt<<<dim3(D_INNER / 128, BL / 128), blk, 0, stream>>>(
        xdbl_f, dtw_bf, dt_raw);

    // 5) chunked selective scan (c = blockIdx.y: concurrent blocks share
    //    chunk c -> xdbl/h_end/Pbuf L2 reuse; R6's swap doubled FETCH)
    k_scan_p1<<<dim3(BATCH * D_INNER / 64, NCHUNK - 1), blk, 0, stream>>>(
        x_bf, dt_raw, dt_proj_b, xdbl_f, A_log, h_end, Pbuf);
    k_scan_p3<<<dim3(BATCH * D_INNER / 64, NCHUNK), blk, 0, stream>>>(
        x_bf, y_bf, dt_raw, dt_proj_b, xdbl_f, xz_bf, A_log, Dvec, h_end, Pbuf);

    // 6) out_proj split-K=2 -> partials (coalesced), then reduce into d_out
    k_gemm_outproj<<<dim3(D_MODEL / 128, BL / 128, OUT_SPLITS), blk, 0, stream>>>(
        y_bf, opw_bf, op_part);
    k_reduce_out<<<dim3(BL * D_MODEL / 4 / 256), blk, 0, stream>>>(op_part, out);
}

// Round 8
// 441.848 us; speedup vs baseline: 1.1008x; 1.0226x over previous
//
#include <hip/hip_runtime.h>
#include <cstdint>
#include <cstddef>

// ---- problem constants ----
#define D_MODEL 2048
#define D_INNER 4096
#define D_IN2   8192
#define D_STATE 16
#define D_CONVK 4
#define DT_RANK 128
#define BATCH   2
#define SEQLEN  1024
#define BL      (BATCH*SEQLEN)
#define XDBL_N  (DT_RANK + 2*D_STATE)   // 160
#define XPW_NPAD 256
#define XPROJ_SPLITS 8
#define OUT_SPLITS 2

// chunked-scan constants
#define NCHUNK  16
#define LCHUNK  (SEQLEN/NCHUNK)         // 64
#define CHW     (BATCH*D_INNER*D_STATE) // 131072

// fused-cast segment block counts (256 thr/block, 1 uint4 out/thread)
#define NB_HID   2048
#define NB_IPW   8192
#define NB_XPW   320
#define NB_XPWZ  192
#define NB_DTW   256
#define NB_OPW   4096
#define NB_XDBLZ 320

typedef short  s8v  __attribute__((ext_vector_type(8)));
typedef float  f4v  __attribute__((ext_vector_type(4)));

__device__ __forceinline__ float softplus_f(float v) {
    return (v > 20.f) ? v : log1pf(__expf(v));
}
__device__ __forceinline__ float silu_f(float v) {
    return v / (1.f + __expf(-v));
}
// native 2^x (v_exp_f32): __expf emits mul-by-log2e + v_exp; folding log2e
// into the precomputed A coefficient saves the mul in the 87%-VALU t-loop.
__device__ __forceinline__ float exp2_f(float x) {
    float r; asm("v_exp_f32 %0, %1" : "=v"(r) : "v"(x)); return r;
}
__device__ __forceinline__ float bf2f(short s) {
    return __uint_as_float(((uint32_t)(uint16_t)s) << 16);
}
__device__ __forceinline__ uint16_t f2bf(float f) {
    uint32_t u = __float_as_uint(f);
    return (uint16_t)((u + 0x7FFFu + ((u >> 16) & 1u)) >> 16);
}
__device__ __forceinline__ uint32_t packbf(float lo, float hi) {
    return ((uint32_t)f2bf(hi) << 16) | (uint32_t)f2bf(lo);
}
__device__ __forceinline__ float quad_sum(float p) {
    p += __int_as_float(__builtin_amdgcn_update_dpp(
            0, __float_as_int(p), 0xB1, 0xF, 0xF, true));
    p += __int_as_float(__builtin_amdgcn_update_dpp(
            0, __float_as_int(p), 0x4E, 0xF, 0xF, true));
    return p;
}

#define GLD16(gp, lp)                                                          \
    __builtin_amdgcn_global_load_lds(                                          \
        (const __attribute__((address_space(1))) void*)(gp),                   \
        (__attribute__((address_space(3))) void*)(lp), 16, 0, 0)

// ---- fused: all fp32->bf16 casts + zero-fills, one dispatch ----
__global__ __launch_bounds__(256)
void k_cast_all(const float* __restrict__ s0, uint32_t* __restrict__ d0,
                const float* __restrict__ s1, uint32_t* __restrict__ d1,
                const float* __restrict__ s2, uint32_t* __restrict__ d2,
                const float* __restrict__ s3, uint32_t* __restrict__ d3,
                const float* __restrict__ s4, uint32_t* __restrict__ d4,
                uint32_t* __restrict__ z0, uint32_t* __restrict__ z1)
{
    int blk = blockIdx.x;
    const float* src = nullptr; uint32_t* dst; int base; int zero = 0;
    if      (blk < NB_HID) { src = s0; dst = d0; base = blk; }
    else if ((blk -= NB_HID)  < NB_IPW)  { src = s1; dst = d1; base = blk; }
    else if ((blk -= NB_IPW)  < NB_XPW)  { src = s2; dst = d2; base = blk; }
    else if ((blk -= NB_XPW)  < NB_XPWZ) { dst = z0; base = blk; zero = 1; }
    else if ((blk -= NB_XPWZ) < NB_DTW)  { src = s3; dst = d3; base = blk; }
    else if ((blk -= NB_DTW)  < NB_OPW)  { src = s4; dst = d4; base = blk; }
    else                                 { dst = z1; base = blk - NB_OPW; zero = 1; }
    const int i = base * 256 + threadIdx.x;
    if (zero) { ((uint4*)dst)[i] = make_uint4(0u, 0u, 0u, 0u); return; }
    const float4 a = ((const float4*)src)[i * 2];
    const float4 b = ((const float4*)src)[i * 2 + 1];
    uint4 o;
    o.x = packbf(a.x, a.y); o.y = packbf(a.z, a.w);
    o.z = packbf(b.x, b.y); o.w = packbf(b.z, b.w);
    ((uint4*)dst)[i] = o;
}

// ==== in_proj: 256x256 4-phase pipelined bf16 GEMM (counted vmcnt) ====
// 512 thr = 8 waves (2M x 4N); per-wave C 128x64 (acc 8x4 f32x4 = 128 VGPR).
// LDS 128 KiB: A[2buf][2kh][256r][32k] + B same; kh = K-half of BK=64.
// Per tile t (4 phases): P0 {rd kh0 m0-3 + B; stage A.kh1(t+1)},
// P1 {rd kh0 m4-7; stage B.kh1(t+1)}, P2 {rd kh1 m0-3 + B; stage A.kh0(t+2)},
// P3 {rd kh1 m4-7; stage B.kh0(t+2); vmcnt(4)}. Raceless proof: vmcnt(4) at
// P3(t-1) leaves newest {B.kh0(t+1),A.kh0(t+1)} outstanding => kh1(t) and
// kh0(t) guaranteed before their first reads; prologue stages kh0(0),kh1(0),
// kh0(1) then vmcnt(4); tail t>=NT-2 uses vmcnt(0). (Round-1's failed
// attempt had vmcnt(8) -- a latent B-half race; this is the corrected port
// of the verified m201 geometry.) Epilogue: 256x256 bf16 tile through the
// staging-LDS union (exact 128 KB fit) -> 512B-coalesced uint4 streams.
__global__ __launch_bounds__(512, 2)
void k_gemm_inproj(const short* __restrict__ A, const short* __restrict__ W,
                   short* __restrict__ C)
{
    constexpr int LDA = D_MODEL;      // 2048
    constexpr int LDC = D_IN2;        // 8192
    constexpr int NT  = D_MODEL / 64; // 32 K-tiles

    __shared__ __align__(16) short smem[65536];   // 128 KiB

    const int tid = threadIdx.x;
    const int w   = tid >> 6;
    const int L   = tid & 63;
    const int bm  = blockIdx.y * 256;
    const int bn  = blockIdx.x * 256;

    // staging addresses: global pre-swizzled, LDS linear (wave-uniform base)
    const int srow = tid >> 2;                       // row 0..127 (j adds 128)
    const int g    = ((tid & 3) - (tid >> 3)) & 3;   // logical k-group
    const short* Ag0 = A + (size_t)(bm + srow) * LDA + g * 8;
    const short* Ag1 = Ag0 + (size_t)128 * LDA;
    const short* Wg0 = W + (size_t)(bn + srow) * LDA + g * 8;
    const short* Wg1 = Wg0 + (size_t)128 * LDA;
    const int wofs = w * 512;                        // shorts

#define STG_A(t_, kh_) do {                                                    \
        GLD16(Ag0 + (size_t)(t_) * 64 + (kh_) * 32,                            \
              smem + (((t_) & 1) * 16384 + (kh_) * 8192 + wofs));              \
        GLD16(Ag1 + (size_t)(t_) * 64 + (kh_) * 32,                            \
              smem + (((t_) & 1) * 16384 + (kh_) * 8192 + 4096 + wofs));       \
    } while (0)
#define STG_B(t_, kh_) do {                                                    \
        GLD16(Wg0 + (size_t)(t_) * 64 + (kh_) * 32,                            \
              smem + (32768 + ((t_) & 1) * 16384 + (kh_) * 8192 + wofs));      \
        GLD16(Wg1 + (size_t)(t_) * 64 + (kh_) * 32,                            \
              smem + (32768 + ((t_) & 1) * 16384 + (kh_) * 8192 + 4096 + wofs));\
    } while (0)

    // fragment read offsets (within one [256][32] K-half), shorts
    const int wm = w >> 2;          // 0..1 -> 128-row A half
    const int wn = w & 3;           // 0..3 -> 64-row B quarter
    const int cl = L & 15;
    const int qd = L >> 4;
    const int slot  = (qd + (cl >> 1)) & 3;
    const int abase = (wm * 128 + cl) * 32 + slot * 8;   // + mt*512
    const int bbase = (wn * 64 + cl) * 32 + slot * 8;    // + nt*512

    f4v acc[8][4];
#pragma unroll
    for (int i = 0; i < 8; i++)
#pragma unroll
        for (int j = 0; j < 4; j++) acc[i][j] = (f4v){0.f, 0.f, 0.f, 0.f};

#define LDS8(p) (*(const s8v*)(p))
#define MF(m_, n_, aa_, bb_)                                                   \
    acc[m_][n_] = __builtin_amdgcn_mfma_f32_16x16x32_bf16(                     \
        aa_, bb_, acc[m_][n_], 0, 0, 0)
#define MF16(m0_)                                                              \
    MF(m0_ + 0, 0, a0, b0); MF(m0_ + 1, 0, a1, b0);                            \
    MF(m0_ + 2, 0, a2, b0); MF(m0_ + 3, 0, a3, b0);                            \
    MF(m0_ + 0, 1, a0, b1); MF(m0_ + 1, 1, a1, b1);                            \
    MF(m0_ + 2, 1, a2, b1); MF(m0_ + 3, 1, a3, b1);                            \
    MF(m0_ + 0, 2, a0, b2); MF(m0_ + 1, 2, a1, b2);                            \
    MF(m0_ + 2, 2, a2, b2); MF(m0_ + 3, 2, a3, b2);                            \
    MF(m0_ + 0, 3, a0, b3); MF(m0_ + 1, 3, a1, b3);                            \
    MF(m0_ + 2, 3, a2, b3); MF(m0_ + 3, 3, a3, b3)
#define PH_SYNC() do {                                                         \
        __builtin_amdgcn_s_barrier();                                          \
        asm volatile("s_waitcnt lgkmcnt(0)" ::: "memory");                     \
        __builtin_amdgcn_sched_barrier(0);                                     \
    } while (0)

    // ---- prologue: kh0(0), kh1(0), kh0(1); all but newest 4 complete ----
    STG_A(0, 0); STG_B(0, 0);
    __builtin_amdgcn_sched_barrier(0);
    STG_A(0, 1); STG_B(0, 1);
    __builtin_amdgcn_sched_barrier(0);
    STG_A(1, 0); STG_B(1, 0);
    asm volatile("s_waitcnt vmcnt(4)" ::: "memory");
    __builtin_amdgcn_s_barrier();

#pragma unroll 2
    for (int t = 0; t < NT; ++t) {
        const short* pA = smem + (t & 1) * 16384;
        const short* pB = smem + 32768 + (t & 1) * 16384;
        s8v a0, a1, a2, a3, b0, b1, b2, b3;

        // ---- P0: kh0, m0-3 + all B ----
        a0 = LDS8(pA + abase);        a1 = LDS8(pA + abase + 512);
        a2 = LDS8(pA + abase + 1024); a3 = LDS8(pA + abase + 1536);
        b0 = LDS8(pB + bbase);        b1 = LDS8(pB + bbase + 512);
        b2 = LDS8(pB + bbase + 1024); b3 = LDS8(pB + bbase + 1536);
        if (t + 1 < NT) STG_A(t + 1, 1);
        PH_SYNC();
        __builtin_amdgcn_s_setprio(1);
        MF16(0);
        __builtin_amdgcn_s_setprio(0);
        __builtin_amdgcn_s_barrier();

        // ---- P1: kh0, m4-7 (B reused) ----
        a0 = LDS8(pA + abase + 2048); a1 = LDS8(pA + abase + 2560);
        a2 = LDS8(pA + abase + 3072); a3 = LDS8(pA + abase + 3584);
        if (t + 1 < NT) STG_B(t + 1, 1);
        PH_SYNC();
        __builtin_amdgcn_s_setprio(1);
        MF16(4);
        __builtin_amdgcn_s_setprio(0);
        __builtin_amdgcn_s_barrier();

        // ---- P2: kh1, m0-3 + all B ----
        a0 = LDS8(pA + 8192 + abase);        a1 = LDS8(pA + 8192 + abase + 512);
        a2 = LDS8(pA + 8192 + abase + 1024); a3 = LDS8(pA + 8192 + abase + 1536);
        b0 = LDS8(pB + 8192 + bbase);        b1 = LDS8(pB + 8192 + bbase + 512);
        b2 = LDS8(pB + 8192 + bbase + 1024); b3 = LDS8(pB + 8192 + bbase + 1536);
        if (t + 2 < NT) STG_A(t + 2, 0);
        PH_SYNC();
        __builtin_amdgcn_s_setprio(1);
        MF16(0);
        __builtin_amdgcn_s_setprio(0);
        __builtin_amdgcn_s_barrier();

        // ---- P3: kh1, m4-7; per-tile counted vmcnt ----
        a0 = LDS8(pA + 8192 + abase + 2048); a1 = LDS8(pA + 8192 + abase + 2560);
        a2 = LDS8(pA + 8192 + abase + 3072); a3 = LDS8(pA + 8192 + abase + 3584);
        if (t + 2 < NT) STG_B(t + 2, 0);
        PH_SYNC();
        __builtin_amdgcn_s_setprio(1);
        MF16(4);
        __builtin_amdgcn_s_setprio(0);
        if (t < NT - 2) asm volatile("s_waitcnt vmcnt(4)" ::: "memory");
        else            asm volatile("s_waitcnt vmcnt(0)" ::: "memory");
        __builtin_amdgcn_s_barrier();
    }
#undef MF16
#undef MF
#undef LDS8
#undef STG_A
#undef STG_B
#undef PH_SYNC

    // ---- epilogue: full 256x256 bf16 tile via LDS union, coalesced out ----
    {
        ushort (*sC)[256] = (ushort(*)[256])smem;
#pragma unroll
        for (int mt = 0; mt < 8; mt++)
#pragma unroll
            for (int nt = 0; nt < 4; nt++)
#pragma unroll
                for (int r = 0; r < 4; r++)
                    sC[wm * 128 + mt * 16 + qd * 4 + r][wn * 64 + nt * 16 + cl] =
                        (ushort)f2bf(acc[mt][nt][r]);
        asm volatile("s_waitcnt lgkmcnt(0)" ::: "memory");
        __builtin_amdgcn_s_barrier();
#pragma unroll
        for (int it = 0; it < 16; it++) {
            const int idx = it * 512 + tid;
            const int row = idx >> 5;
            const int c8s = (idx & 31) * 8;     // 16B chunks, 512B/row
            *(uint4*)&C[(size_t)(bm + row) * LDC + bn + c8s] =
                *(const uint4*)&sC[row][c8s];
        }
    }
}

// ---- bf16 MFMA GEMM body (128^2): C[m,n] = sum_k A[m,k]*W[n,k] ----
// EPI: 0 = fp32 LDS-coalesced store to slice blockIdx.z,
//      3 = fp32 atomicAdd (xproj, tiny output).
template<int EPI>
__device__ __forceinline__
void gemm_body(const short* __restrict__ A, int lda,
               const short* __restrict__ W, int ldw,
               void* __restrict__ Cv, int ldc, int M, int kchunk)
{
    constexpr int SMEM_BYTES = (EPI == 0) ? 33792 : 32768;
    __shared__ __align__(16) char smem[SMEM_BYTES];
    short* sA = (short*)smem;             // 128x64 bf16 = 16 KB
    short* sW = (short*)(smem + 16384);   // 128x64 bf16 = 16 KB

    const int tid = threadIdx.x;
    const int w   = tid >> 6;
    const int L   = tid & 63;
    const int bm  = blockIdx.y * 128;
    const int bn  = blockIdx.x * 128;
    const int k0  = blockIdx.z * kchunk;

    const int rsub = L >> 3;
    const int c8   = (((L & 7) - rsub) & 7) * 8;
    const short* Ag[4]; const short* Wg[4];
#pragma unroll
    for (int j = 0; j < 4; j++) {
        Ag[j] = A + (size_t)(bm + w * 32 + j * 8 + rsub) * lda + c8 + k0;
        Wg[j] = W + (size_t)(bn + w * 32 + j * 8 + rsub) * ldw + c8 + k0;
    }

    const int wm = (w >> 1) * 64;
    const int wn = (w & 1) * 64;
    const int cl = L & 15;
    const int qd = L >> 4;

    f4v acc[4][4];
#pragma unroll
    for (int i = 0; i < 4; i++)
#pragma unroll
        for (int j = 0; j < 4; j++) acc[i][j] = (f4v){0.f, 0.f, 0.f, 0.f};

    for (int k = 0; k < kchunk; k += 64) {
#pragma unroll
        for (int j = 0; j < 4; j++)
            GLD16(Ag[j] + k, &sA[(w * 32 + j * 8) * 64]);
#pragma unroll
        for (int j = 0; j < 4; j++)
            GLD16(Wg[j] + k, &sW[(w * 32 + j * 8) * 64]);
        __syncthreads();
#pragma unroll
        for (int kk = 0; kk < 2; kk++) {
            const int sl = ((kk * 4 + qd + cl) & 7) * 8;
            s8v a[4], b[4];
#pragma unroll
            for (int mt = 0; mt < 4; mt++)
                a[mt] = *(const s8v*)&sA[(wm + mt * 16 + cl) * 64 + sl];
#pragma unroll
            for (int nt = 0; nt < 4; nt++)
                b[nt] = *(const s8v*)&sW[(wn + nt * 16 + cl) * 64 + sl];
#pragma unroll
            for (int mt = 0; mt < 4; mt++)
#pragma unroll
                for (int nt = 0; nt < 4; nt++)
                    acc[mt][nt] = __builtin_amdgcn_mfma_f32_16x16x32_bf16(
                        a[mt], b[nt], acc[mt][nt], 0, 0, 0);
        }
        __syncthreads();   // also fences staging before epilogue smem reuse
    }

    if constexpr (EPI == 0) {
        float (*sC)[132] = (float(*)[132])smem;
        float* Cf = (float*)Cv + (size_t)blockIdx.z * M * ldc;
#pragma unroll
        for (int half = 0; half < 2; half++) {
            __syncthreads();
            if (wm == half * 64) {
#pragma unroll
                for (int mt = 0; mt < 4; mt++)
#pragma unroll
                    for (int nt = 0; nt < 4; nt++)
#pragma unroll
                        for (int r = 0; r < 4; r++)
                            sC[mt * 16 + qd * 4 + r][wn + nt * 16 + cl] =
                                acc[mt][nt][r];
            }
            __syncthreads();
#pragma unroll
            for (int it = 0; it < 8; it++) {
                const int f4  = it * 256 + tid;
                const int row = f4 >> 5;
                const int c4  = (f4 & 31) * 4;
                const float4 v = *(const float4*)&sC[row][c4];
                *(float4*)&Cf[(size_t)(bm + half * 64 + row) * ldc + bn + c4] = v;
            }
        }
    } else {
        float* Cf = (float*)Cv;
#pragma unroll
        for (int mt = 0; mt < 4; mt++) {
            const int row0 = bm + wm + mt * 16 + qd * 4;
#pragma unroll
            for (int nt = 0; nt < 4; nt++) {
                const int col = bn + wn + nt * 16 + cl;
                if (col >= XDBL_N) continue;
#pragma unroll
                for (int r = 0; r < 4; r++)
                    atomicAdd(&Cf[(size_t)(row0 + r) * ldc + col], acc[mt][nt][r]);
            }
        }
    }
}

__global__ __launch_bounds__(256)
void k_gemm_xproj(const short* A, const short* W, float* C)
{ gemm_body<3>(A, D_INNER, W, D_INNER, C, XDBL_N, BL, D_INNER / XPROJ_SPLITS); }

__global__ __launch_bounds__(256)
void k_gemm_outproj(const short* A, const short* W, float* C)
{ gemm_body<0>(A, D_INNER, W, D_INNER, C, D_MODEL, BL, D_INNER / OUT_SPLITS); }

// ---- dt_proj GEMM (fused A-repack, no activation): dt_raw = A @ dtw^T ----
__global__ __launch_bounds__(256)
void k_gemm_dt(const float* __restrict__ Af, const short* __restrict__ W,
               float* __restrict__ C)
{
    __shared__ __align__(16) char smem[65536];
    short* sA = (short*)smem;             // [2][128][64] bf16 = 32 KB
    short* sW = (short*)(smem + 32768);   // [2][128][64] bf16 = 32 KB

    const int tid = threadIdx.x;
    const int w   = tid >> 6;
    const int L   = tid & 63;
    const int bm  = blockIdx.y * 128;
    const int bn  = blockIdx.x * 128;

#pragma unroll
    for (int ci = 0; ci < 8; ci++) {
        const int c_lin = tid * 8 + ci;
        const int r = c_lin >> 4;
        const int c = c_lin & 15;
        const float* src = Af + (size_t)(bm + r) * XDBL_N + c * 8;
        const float4 u = *(const float4*)src;
        const float4 v = *(const float4*)(src + 4);
        const int half = c >> 3, cc = c & 7;
        const int slot = (cc + r) & 7;
        uint4 o;
        o.x = packbf(u.x, u.y); o.y = packbf(u.z, u.w);
        o.z = packbf(v.x, v.y); o.w = packbf(v.z, v.w);
        *(uint4*)&sA[half * 8192 + r * 64 + slot * 8] = o;
    }
    const int rsub = L >> 3;
    const int c8   = (((L & 7) - rsub) & 7) * 8;
#pragma unroll
    for (int half = 0; half < 2; half++)
#pragma unroll
        for (int j = 0; j < 4; j++)
            GLD16(W + (size_t)(bn + w * 32 + j * 8 + rsub) * DT_RANK + half * 64 + c8,
                  &sW[half * 8192 + (w * 32 + j * 8) * 64]);
    __syncthreads();

    const int wm = (w >> 1) * 64;
    const int wn = (w & 1) * 64;
    const int cl = L & 15;
    const int qd = L >> 4;

    f4v acc[4][4];
#pragma unroll
    for (int i = 0; i < 4; i++)
#pragma unroll
        for (int j = 0; j < 4; j++) acc[i][j] = (f4v){0.f, 0.f, 0.f, 0.f};

#pragma unroll
    for (int ks = 0; ks < 4; ks++) {
        const int half = ks >> 1;
        const int sl = (((ks & 1) * 4 + qd + cl) & 7) * 8;
        s8v a[4], b[4];
#pragma unroll
        for (int mt = 0; mt < 4; mt++)
            a[mt] = *(const s8v*)&sA[half * 8192 + (wm + mt * 16 + cl) * 64 + sl];
#pragma unroll
        for (int nt = 0; nt < 4; nt++)
            b[nt] = *(const s8v*)&sW[half * 8192 + (wn + nt * 16 + cl) * 64 + sl];
#pragma unroll
        for (int mt = 0; mt < 4; mt++)
#pragma unroll
            for (int nt = 0; nt < 4; nt++)
                acc[mt][nt] = __builtin_amdgcn_mfma_f32_16x16x32_bf16(
                    a[mt], b[nt], acc[mt][nt], 0, 0, 0);
    }

    __syncthreads();   // staging dead; reuse smem for epilogue
    float (*sC)[132] = (float(*)[132])smem;
#pragma unroll
    for (int half = 0; half < 2; half++) {
        __syncthreads();
        if (wm == half * 64) {
#pragma unroll
            for (int mt = 0; mt < 4; mt++)
#pragma unroll
                for (int nt = 0; nt < 4; nt++)
#pragma unroll
                    for (int r = 0; r < 4; r++)
                        sC[mt * 16 + qd * 4 + r][wn + nt * 16 + cl] =
                            acc[mt][nt][r];
        }
        __syncthreads();
#pragma unroll
        for (int it = 0; it < 8; it++) {
            const int f4  = it * 256 + tid;
            const int row = f4 >> 5;
            const int c4  = (f4 & 31) * 4;
            const float4 v = *(const float4*)&sC[row][c4];
            *(float4*)&C[(size_t)(bm + half * 64 + row) * D_INNER + bn + c4] = v;
        }
    }
}

// ---- out_proj split-K reduce: out = P0 + P1 (float4) ----
__global__ __launch_bounds__(256)
void k_reduce_out(const float* __restrict__ P, float* __restrict__ out)
{
    const int i = blockIdx.x * 256 + threadIdx.x;   // float4 index
    const float4 a = ((const float4*)P)[i];
    const float4 b = ((const float4*)(P + (size_t)BL * D_MODEL))[i];
    ((float4*)out)[i] = make_float4(a.x + b.x, a.y + b.y, a.z + b.z, a.w + b.w);
}

// ---- causal depthwise conv1d (K=4) + SiLU ----
__global__ __launch_bounds__(256)
void k_conv(const short* __restrict__ xz_bf, const float* __restrict__ cw,
            const float* __restrict__ cb, short* __restrict__ x_bf)
{
    const int idx = blockIdx.x * 256 + threadIdx.x;
    const int d  = idx & (D_INNER - 1);
    const int bl = idx >> 12;
    const int l  = bl & (SEQLEN - 1);
    const int b  = bl >> 10;
    const short* xb = xz_bf + (size_t)b * SEQLEN * D_IN2 + d;
    float acc = cb[d];
#pragma unroll
    for (int k = 0; k < D_CONVK; k++) {
        const int ll = l + k - (D_CONVK - 1);
        if (ll >= 0) acc = fmaf(bf2f(xb[(size_t)ll * D_IN2]), cw[d * D_CONVK + k], acc);
    }
    x_bf[idx] = (short)f2bf(silu_f(acc));
}

// ================= chunked selective scan =================
__global__ __launch_bounds__(256)
void k_scan_p1(const short* __restrict__ x_bf, const float* __restrict__ dtr,
               const float* __restrict__ dtb, const float* __restrict__ xdbl,
               const float* __restrict__ A_log,
               float* __restrict__ h_end, float* __restrict__ Pprod)
{
    const int c   = blockIdx.y;
    const int ch0 = blockIdx.x * 64;
    const int b   = ch0 >> 12;
    const int d0  = ch0 & (D_INNER - 1);
    const int tid = threadIdx.x;
    const int g   = tid >> 2;
    const int q   = tid & 3;
    const int d   = d0 + g;

    const float LOG2E = 1.44269504f;
    const float4 Al = *(const float4*)&A_log[(d << 4) + (q << 2)];
    float An[4] = {-__expf(Al.x) * LOG2E, -__expf(Al.y) * LOG2E,
                   -__expf(Al.z) * LOG2E, -__expf(Al.w) * LOG2E};
    float h[4]  = {0.f, 0.f, 0.f, 0.f};
    float Pp[4] = {1.f, 1.f, 1.f, 1.f};

    __shared__ float s_x [16][68];
    __shared__ float s_dt[16][68];
    __shared__ float s_B [16][20];

    const int lt  = tid >> 4;
    const int ld4 = (tid & 15) * 4;
    const float4 bb = *(const float4*)&dtb[d0 + ld4];

    for (int sub = 0; sub < LCHUNK / 16; sub++) {
        const int l0 = c * LCHUNK + sub * 16;
        const size_t bl = (size_t)(b * SEQLEN + l0 + lt);
        __syncthreads();
        {
            const short4 sx = *(const short4*)&x_bf[bl * D_INNER + d0 + ld4];
            const float4 dv = *(const float4*)&dtr[bl * D_INNER + d0 + ld4];
            *(float4*)&s_x [lt][ld4] =
                make_float4(bf2f(sx.x), bf2f(sx.y), bf2f(sx.z), bf2f(sx.w));
            *(float4*)&s_dt[lt][ld4] = make_float4(
                softplus_f(dv.x + bb.x), softplus_f(dv.y + bb.y),
                softplus_f(dv.z + bb.z), softplus_f(dv.w + bb.w));
            if (tid < 64) {
                const int t2 = tid >> 2, k = (tid & 3) * 4;
                const size_t bl2 = (size_t)(b * SEQLEN + l0 + t2);
                *(float4*)&s_B[t2][k] =
                    *(const float4*)&xdbl[bl2 * XDBL_N + DT_RANK + k];
            }
        }
        __syncthreads();
#pragma unroll
        for (int t = 0; t < 16; t++) {
            const float xv  = s_x [t][g];
            const float dtv = s_dt[t][g];
            const float4 Bq = *(const float4*)&s_B[t][q * 4];
            const float Bv[4] = {Bq.x, Bq.y, Bq.z, Bq.w};
            const float dtx = dtv * xv;
#pragma unroll
            for (int j = 0; j < 4; j++) {
                const float dA = exp2_f(dtv * An[j]);
                h[j]  = fmaf(h[j], dA, dtx * Bv[j]);
                Pp[j] *= dA;
            }
        }
    }
    const size_t i0 = (size_t)c * CHW + (((size_t)(b * D_INNER + d)) << 4) + (q << 2);
    *(float4*)&h_end[i0] = make_float4(h[0], h[1], h[2], h[3]);
    *(float4*)&Pprod[i0] = make_float4(Pp[0], Pp[1], Pp[2], Pp[3]);
}

__global__ __launch_bounds__(256)
void k_scan_p3(const short* __restrict__ x_bf, short* __restrict__ y_bf,
               const float* __restrict__ dtr, const float* __restrict__ dtb,
               const float* __restrict__ xdbl,
               const short* __restrict__ xz_bf, const float* __restrict__ A_log,
               const float* __restrict__ Dvec,
               const float* __restrict__ h_end, const float* __restrict__ Pbuf)
{
    const int c   = blockIdx.y;
    const int ch0 = blockIdx.x * 64;
    const int b   = ch0 >> 12;
    const int d0  = ch0 & (D_INNER - 1);
    const int tid = threadIdx.x;
    const int g   = tid >> 2;
    const int q   = tid & 3;
    const int d   = d0 + g;

    const float LOG2E = 1.44269504f;
    const float4 Al = *(const float4*)&A_log[(d << 4) + (q << 2)];
    float An[4] = {-__expf(Al.x) * LOG2E, -__expf(Al.y) * LOG2E,
                   -__expf(Al.z) * LOG2E, -__expf(Al.w) * LOG2E};
    const float Dd = Dvec[d];

    // ---- prefix carry: batch-4 loads, ascending-j fma chain (bit-identical)
    float h[4] = {0.f, 0.f, 0.f, 0.f};
    const size_t base = (((size_t)(b * D_INNER + d)) << 4) + (q << 2);
    {
        int j = 0;
        for (; j + 4 <= c; j += 4) {
            float4 he[4], Pq[4];
#pragma unroll
            for (int u = 0; u < 4; u++) {
                he[u] = *(const float4*)&h_end[(size_t)(j + u) * CHW + base];
                Pq[u] = *(const float4*)&Pbuf [(size_t)(j + u) * CHW + base];
            }
#pragma unroll
            for (int u = 0; u < 4; u++) {
                h[0] = fmaf(Pq[u].x, h[0], he[u].x);
                h[1] = fmaf(Pq[u].y, h[1], he[u].y);
                h[2] = fmaf(Pq[u].z, h[2], he[u].z);
                h[3] = fmaf(Pq[u].w, h[3], he[u].w);
            }
        }
        for (; j < c; j++) {
            const float4 he = *(const float4*)&h_end[(size_t)j * CHW + base];
            const float4 Pq = *(const float4*)&Pbuf [(size_t)j * CHW + base];
            h[0] = fmaf(Pq.x, h[0], he.x);
            h[1] = fmaf(Pq.y, h[1], he.y);
            h[2] = fmaf(Pq.z, h[2], he.z);
            h[3] = fmaf(Pq.w, h[3], he.w);
        }
    }

    __shared__ float s_x [16][68];
    __shared__ float s_dt[16][68];
    __shared__ float s_z [16][68];   // holds silu(z), precomputed at staging
    __shared__ float s_B [16][20];
    __shared__ float s_C [16][20];

    const int lt  = tid >> 4;
    const int ld4 = (tid & 15) * 4;
    const float4 bb = *(const float4*)&dtb[d0 + ld4];

    for (int sub = 0; sub < LCHUNK / 16; sub++) {
        const int l0 = c * LCHUNK + sub * 16;
        const size_t bl = (size_t)(b * SEQLEN + l0 + lt);
        __syncthreads();
        {
            const short4 sx = *(const short4*)&x_bf[bl * D_INNER + d0 + ld4];
            const float4 dv = *(const float4*)&dtr[bl * D_INNER + d0 + ld4];
            const short4 zv = *(const short4*)&xz_bf[bl * D_IN2 + D_INNER + d0 + ld4];
            *(float4*)&s_x [lt][ld4] =
                make_float4(bf2f(sx.x), bf2f(sx.y), bf2f(sx.z), bf2f(sx.w));
            *(float4*)&s_dt[lt][ld4] = make_float4(
                softplus_f(dv.x + bb.x), softplus_f(dv.y + bb.y),
                softplus_f(dv.z + bb.z), softplus_f(dv.w + bb.w));
            *(float4*)&s_z [lt][ld4] = make_float4(
                silu_f(bf2f(zv.x)), silu_f(bf2f(zv.y)),
                silu_f(bf2f(zv.z)), silu_f(bf2f(zv.w)));
            if (tid < 128) {
                const int t2 = (tid & 63) >> 2, k = (tid & 3) * 4;
                const size_t bl2 = (size_t)(b * SEQLEN + l0 + t2);
                const int off = (tid < 64) ? 0 : D_STATE;
                const float4 v =
                    *(const float4*)&xdbl[bl2 * XDBL_N + DT_RANK + off + k];
                if (tid < 64) *(float4*)&s_B[t2][k] = v;
                else          *(float4*)&s_C[t2][k] = v;
            }
        }
        __syncthreads();
        const size_t orow = (size_t)(b * SEQLEN + l0);
#pragma unroll
        for (int t = 0; t < 16; t++) {
            const float xv  = s_x [t][g];
            const float dtv = s_dt[t][g];
            const float4 Bq = *(const float4*)&s_B[t][q * 4];
            const float4 Cq = *(const float4*)&s_C[t][q * 4];
            const float Bv[4] = {Bq.x, Bq.y, Bq.z, Bq.w};
            const float Cv[4] = {Cq.x, Cq.y, Cq.z, Cq.w};
            const float dtx = dtv * xv;
            float p = 0.f;
#pragma unroll
            for (int j = 0; j < 4; j++) {
                const float dA = exp2_f(dtv * An[j]);
                h[j] = fmaf(h[j], dA, dtx * Bv[j]);
                p = fmaf(h[j], Cv[j], p);
            }
            p = quad_sum(p);
            if (q == 0) {
                const float yv = fmaf(xv, Dd, p) * s_z[t][g];
                y_bf[(orow + t) * D_INNER + d] = (short)f2bf(yv);
            }
        }
    }
}

extern "C" void kernel_launch(void* const* d_in, const int* in_sizes, int n_in,
                              void* d_out, int out_size, void* d_ws, size_t ws_size,
                              hipStream_t stream)
{
    const float* hidden     = (const float*)d_in[0];
    const float* in_proj_w  = (const float*)d_in[1];
    const float* conv_w     = (const float*)d_in[2];
    const float* conv_b     = (const float*)d_in[3];
    const float* x_proj_w   = (const float*)d_in[4];
    const float* dt_proj_w  = (const float*)d_in[5];
    const float* dt_proj_b  = (const float*)d_in[6];
    const float* A_log      = (const float*)d_in[7];
    const float* Dvec       = (const float*)d_in[8];
    const float* out_proj_w = (const float*)d_in[9];
    float* out = (float*)d_out;

    // ---- workspace layout (stream-ordered aliasing, ~140.3 MB) ----
    const size_t MB = 1ull << 20;
    char* ws = (char*)d_ws;
    short* xz_bf   = (short*)(ws);                  // [0,32)   bf16 [BL,8192]
    short* x_bf    = (short*)(ws + 32 * MB);        // [32,48)  bf16 [BL,4096]
    short* ipw_bf  = (short*)(ws + 48 * MB);        // [48,80)  dead after in_proj
    short* y_bf    = (short*)(ws + 48 * MB);        // alias (phase3)
    float* h_end   = (float*)(ws + 64 * MB);        // [64,72)  alias (phase1)
    float* Pbuf    = (float*)(ws + 72 * MB);        // [72,80)  alias (phase1)
    short* hid_bf  = (short*)(ws + 80 * MB);        // [80,88)  dead after in_proj
    short* opw_bf  = (short*)(ws + 88 * MB);        // [88,104)
    float* dt_raw  = (float*)(ws + 104 * MB);       // [104,136) live thru p3
    float* op_part = (float*)(ws + 104 * MB);       // alias: outproj partials (after p3)
    short* xpw_bf  = (short*)(ws + 136 * MB);       // [136,138)
    short* dtw_bf  = (short*)(ws + 138 * MB);       // [138,139)
    float* xdbl_f  = (float*)(ws + 139 * MB);       // 1.25 MB, atomic target

    const dim3 blk(256);

    // 0) fused casts + zero-fills
    k_cast_all<<<dim3(NB_HID + NB_IPW + NB_XPW + NB_XPWZ + NB_DTW + NB_OPW + NB_XDBLZ),
                blk, 0, stream>>>(
        hidden, (uint32_t*)hid_bf, in_proj_w, (uint32_t*)ipw_bf,
        x_proj_w, (uint32_t*)xpw_bf, dt_proj_w, (uint32_t*)dtw_bf,
        out_proj_w, (uint32_t*)opw_bf,
        (uint32_t*)(xpw_bf + (size_t)XDBL_N * D_INNER),
        (uint32_t*)xdbl_f);

    // 1) in_proj -> xz_bf: 256^2 4-phase pipelined GEMM, 256 blocks = 1/CU
    k_gemm_inproj<<<dim3(D_IN2 / 256, BL / 256), dim3(512), 0, stream>>>(
        hid_bf, ipw_bf, xz_bf);

    // 2) conv + SiLU -> x_bf
    k_conv<<<dim3((BL * D_INNER) / 256), blk, 0, stream>>>(
        xz_bf, conv_w, conv_b, x_bf);

    // 3) x_proj split-K=8: atomicAdd into xdbl_f
    k_gemm_xproj<<<dim3(XPW_NPAD / 128, BL / 128, XPROJ_SPLITS), blk, 0, stream>>>(
        x_bf, xpw_bf, xdbl_f);

    // 4) dt_proj GEMM (fused A-repack, no activation) -> dt_raw;
    //    bias+softplus are applied at the scans' dt-load.
    k_gemm_dt<<<dim3(D_INNER / 128, BL / 128), blk, 0, stream>>>(
        xdbl_f, dtw_bf, dt_raw);

    // 5) chunked selective scan (c = blockIdx.y for L2 locality)
    k_scan_p1<<<dim3(BATCH * D_INNER / 64, NCHUNK - 1), blk, 0, stream>>>(
        x_bf, dt_raw, dt_proj_b, xdbl_f, A_log, h_end, Pbuf);
    k_scan_p3<<<dim3(BATCH * D_INNER / 64, NCHUNK), blk, 0, stream>>>(
        x_bf, y_bf, dt_raw, dt_proj_b, xdbl_f, xz_bf, A_log, Dvec, h_end, Pbuf);

    // 6) out_proj split-K=2 -> partials (coalesced), then reduce into d_out
    k_gemm_outproj<<<dim3(D_MODEL / 128, BL / 128, OUT_SPLITS), blk, 0, stream>>>(
        y_bf, opw_bf, op_part);
    k_reduce_out<<<dim3(BL * D_MODEL / 4 / 256), blk, 0, stream>>>(op_part, out);
}